// Round 14
// baseline (1702.656 us; speedup 1.0000x reference)
//
#include <hip/hip_runtime.h>
#include <hip/hip_fp16.h>

#define N_NODES_C 100000
#define N_EDGES_C 1200000
#define NBUK ((N_NODES_C + 255) >> 8)   // 391 buckets of 256 nodes
#define CHUNK 4096                       // edges per binning block

typedef _Float16 f16x8 __attribute__((ext_vector_type(8)));
typedef float f32x4 __attribute__((ext_vector_type(4)));

// ---------- bucket-level histogram: LDS aggregate, ~115k global atomics ----------
__global__ __launch_bounds__(256) void bucket_hist(const int* __restrict__ ei,
                                                   int* __restrict__ bucket_cnt, int nedges) {
    __shared__ int cnt[NBUK];
    const int tid = threadIdx.x;
    const int base = blockIdx.x * CHUNK;
    const int nloc = min(CHUNK, nedges - base);
    for (int i = tid; i < NBUK; i += 256) cnt[i] = 0;
    __syncthreads();
    for (int i = tid; i < nloc; i += 256) atomicAdd(&cnt[ei[base + i] >> 8], 1);
    __syncthreads();
    for (int b = tid; b < NBUK; b += 256) {
        int n = cnt[b];
        if (n) atomicAdd(&bucket_cnt[b], n);
    }
}

// ---------- scan 391 bucket counts -> bucket_base / bucket_next ----------
__global__ void bucket_scan(const int* __restrict__ bucket_cnt, int* __restrict__ bucket_base,
                            int* __restrict__ bucket_next, int nb) {
    if (threadIdx.x == 0 && blockIdx.x == 0) {
        int acc = 0;
        for (int i = 0; i < nb; ++i) {
            bucket_base[i] = acc;
            bucket_next[i] = acc;
            acc += bucket_cnt[i];
        }
        bucket_base[nb] = acc;
    }
}

// ---------- phase B: LDS-binned staging of (r,c) grouped by 256-node bucket ----------
__global__ __launch_bounds__(256) void bin_stage(const int* __restrict__ ei,
                                                 int* __restrict__ bucket_next,
                                                 int2* __restrict__ staged, int nedges) {
    __shared__ int cnt[NBUK];
    __shared__ int ofs[NBUK];
    __shared__ int run[NBUK];
    __shared__ int gbase[NBUK];
    __shared__ int ssum[256];
    __shared__ int2 sedge[CHUNK];
    const int tid = threadIdx.x;
    const int base = blockIdx.x * CHUNK;
    const int nloc = min(CHUNK, nedges - base);

    for (int i = tid; i < NBUK; i += 256) { cnt[i] = 0; run[i] = 0; }
    __syncthreads();

    int r[16], c[16];
#pragma unroll
    for (int k = 0; k < 16; ++k) {
        int loc = tid + k * 256;
        bool ok = loc < nloc;
        int idx = base + loc;
        r[k] = ok ? ei[idx] : -1;
        c[k] = ok ? ei[nedges + idx] : 0;
        if (ok) atomicAdd(&cnt[r[k] >> 8], 1);
    }
    __syncthreads();

    // exclusive scan of cnt[NBUK] -> ofs
    int a0 = (2 * tid < NBUK) ? cnt[2 * tid] : 0;
    int a1 = (2 * tid + 1 < NBUK) ? cnt[2 * tid + 1] : 0;
    ssum[tid] = a0 + a1;
    __syncthreads();
    for (int off = 1; off < 256; off <<= 1) {
        int v = ssum[tid];
        int add = (tid >= off) ? ssum[tid - off] : 0;
        __syncthreads();
        ssum[tid] = v + add;
        __syncthreads();
    }
    int excl = (tid > 0) ? ssum[tid - 1] : 0;
    if (2 * tid < NBUK) ofs[2 * tid] = excl;
    if (2 * tid + 1 < NBUK) ofs[2 * tid + 1] = excl + a0;
    __syncthreads();

    // place edges into LDS grouped by bucket
#pragma unroll
    for (int k = 0; k < 16; ++k) {
        if (r[k] >= 0) {
            int b = r[k] >> 8;
            int p = atomicAdd(&run[b], 1);
            sedge[ofs[b] + p] = make_int2(r[k], c[k]);
        }
    }
    __syncthreads();

    // allocate global runs (one atomic per non-empty bucket)
    for (int b = tid; b < NBUK; b += 256) {
        int n = cnt[b];
        gbase[b] = n ? atomicAdd(&bucket_next[b], n) : 0;
    }
    __syncthreads();

    // coalesced copy-out: consecutive i are bucket-grouped runs
    for (int i = tid; i < nloc; i += 256) {
        int2 e = sedge[i];
        int b = e.x >> 8;
        staged[gbase[b] + (i - ofs[b])] = e;
    }
}

// ---------- phase C1: per-bucket degree count -> rowptr slice + deg_inv_sqrt ----------
__global__ __launch_bounds__(256) void bin_count(const int2* __restrict__ staged,
                                                 const int* __restrict__ bucket_base,
                                                 int* __restrict__ rowptr, float* __restrict__ dis,
                                                 int nnodes, int nedges) {
    __shared__ int deg[256];
    __shared__ int ssum[256];
    const int b = blockIdx.x;
    const int n0 = b << 8;
    const int nend = min(n0 + 256, nnodes);
    const int nloc = nend - n0;
    const int tid = threadIdx.x;
    deg[tid] = 0;
    __syncthreads();
    const int ebase = bucket_base[b];
    const int ecount = bucket_base[b + 1] - ebase;
    for (int i = tid; i < ecount; i += 256) {
        atomicAdd(&deg[staged[ebase + i].x - n0], 1);
    }
    __syncthreads();
    int d = deg[tid];
    if (tid < nloc) {
        float df = (float)d;
        dis[n0 + tid] = (d > 0) ? (1.0f / sqrtf(fmaxf(df, 1.f))) : 0.f;
    }
    ssum[tid] = d;
    __syncthreads();
    for (int off = 1; off < 256; off <<= 1) {
        int v = ssum[tid];
        int add = (tid >= off) ? ssum[tid - off] : 0;
        __syncthreads();
        ssum[tid] = v + add;
        __syncthreads();
    }
    int excl = (tid > 0) ? ssum[tid - 1] : 0;
    if (tid < nloc) rowptr[n0 + tid] = ebase + excl;
    if (b == NBUK - 1 && tid == 0) rowptr[nnodes] = nedges;
}

// ---------- phase C2: per-bucket exact CSR placement + norm weight ----------
// colw word0 packs col (bits 0..19) and bucket-relative row (bits 20..27).
__global__ __launch_bounds__(256) void bin_place(const int2* __restrict__ staged,
                                                 const int* __restrict__ rowptr,
                                                 const float* __restrict__ dis,
                                                 int2* __restrict__ colw, int nnodes) {
    __shared__ int rp[256];
    __shared__ int nx[256];
    __shared__ float dl[256];
    const int b = blockIdx.x;
    const int n0 = b << 8;
    const int nend = min(n0 + 256, nnodes);
    const int nloc = nend - n0;
    const int tid = threadIdx.x;
    if (tid < nloc) {
        rp[tid] = rowptr[n0 + tid];
        dl[tid] = dis[n0 + tid];
    }
    nx[tid] = 0;
    __syncthreads();
    const int ebase = rowptr[n0];
    const int ecount = rowptr[nend] - ebase;
    for (int i = tid; i < ecount; i += 256) {
        int2 e = staged[ebase + i];
        int rrel = e.x - n0;
        int p = atomicAdd(&nx[rrel], 1);
        float w = -dl[rrel] * dis[e.y];
        colw[rp[rrel] + p] = make_int2(e.y | (rrel << 20), __float_as_int(w));
    }
}

// ---------- pack layer-1 folded weights into MFMA B-fragment layout (fp16) ----------
__global__ void fold_w1f(const float* __restrict__ W, __half* __restrict__ Wf) {
    int i = blockIdx.x * blockDim.x + threadIdx.x;
    if (i >= 4 * 6 * 64 * 8) return;
    int j = i & 7;
    int lane = (i >> 3) & 63;
    int rest = i >> 9;
    int kh = rest % 6;
    int ct = rest / 6;
    int term = kh >> 1;
    int k = ((kh & 1) << 5) | ((lane >> 4) << 3) | j;
    int c = (ct << 4) | (lane & 15);
    float w0 = W[k * 64 + c];
    float w1 = W[4096 + k * 64 + c];
    float w2 = W[2 * 4096 + k * 64 + c];
    float v = (term == 0) ? (w0 - w2) : ((term == 1) ? w1 : 2.0f * w2);
    Wf[i] = __float2half(v);
}

// ---------- pack layer-2 concat weights into MFMA B-fragment layout (fp16) ----------
__global__ void fold_w2f(const float* __restrict__ W, __half* __restrict__ Wf) {
    int i = blockIdx.x * blockDim.x + threadIdx.x;
    if (i >= 6 * 2 * 64 * 8) return;
    int j = i & 7;
    int lane = (i >> 3) & 63;
    int rest = i >> 9;
    int kh = rest & 1;
    int ct = rest >> 1;
    int k = (kh << 5) | ((lane >> 4) << 3) | j;
    int cg = ct * 16 + (lane & 15);
    int seg = cg >> 5;
    int c = cg & 31;
    float w0 = W[k * 32 + c];
    float w1 = W[2048 + k * 32 + c];
    float w2 = W[2 * 2048 + k * 32 + c];
    float v = (seg == 0) ? (w0 - w2) : ((seg == 1) ? w1 : 2.0f * w2);
    Wf[i] = __float2half(v);
}

// ---------- fp32 -> fp16 feature conversion (4 elems/thread) ----------
__global__ void f2h_kernel(const float* __restrict__ in, __half* __restrict__ out, int n4) {
    int i = blockIdx.x * blockDim.x + threadIdx.x;
    if (i >= n4) return;
    float4 v = ((const float4*)in)[i];
    __half2 tmp[2];
    tmp[0] = __floats2half2_rn(v.x, v.y);
    tmp[1] = __floats2half2_rn(v.z, v.w);
    ((float2*)out)[i] = *(float2*)tmp;
}

// ---------- prop64_b: block = 128 nodes; edge-parallel gather + LDS fp32 scatter ----------
// 16 lanes/edge (4 ch each, 8B gather), 16 edges per block-iteration -> high MLP.
// LDS accum stride 64: ds_add bank aliasing is 2-way (free).
__global__ __launch_bounds__(256) void prop64_b(const __half* __restrict__ t,
                                                const int* __restrict__ rowptr,
                                                const int2* __restrict__ colw,
                                                __half* __restrict__ out, int nnodes) {
    __shared__ float acc[128 * 64];   // 32 KB
    const int tid = threadIdx.x;
    const int n0 = blockIdx.x * 128;
    const int nend = min(n0 + 128, nnodes);
    for (int i = tid; i < 128 * 64; i += 256) acc[i] = 0.f;
    __syncthreads();
    const int es = rowptr[n0];
    const int ee = rowptr[nend];
    const int off = n0 & 128;          // position within parent 256-bucket
    const int cq = tid & 15;
    for (int e = es + (tid >> 4); e < ee; e += 16) {
        int2 cw = colw[e];
        int c = cw.x & 0xFFFFF;
        int rloc = (cw.x >> 20) - off;
        float w = __int_as_float(cw.y);
        float2 raw = ((const float2*)(t + (size_t)c * 64))[cq];
        const __half2* h = (const __half2*)&raw;
        float2 f0 = __half22float2(h[0]);
        float2 f1 = __half22float2(h[1]);
        float* ap = acc + rloc * 64 + cq * 4;
        atomicAdd(ap + 0, w * f0.x);
        atomicAdd(ap + 1, w * f0.y);
        atomicAdd(ap + 2, w * f1.x);
        atomicAdd(ap + 3, w * f1.y);
    }
    __syncthreads();
    for (int i = tid; i < 128 * 32; i += 256) {   // 128 rows x 32 half2
        int rl = i >> 5;
        int n = n0 + rl;
        if (n >= nnodes) break;
        int ch2 = i & 31;
        __half2 v = __floats2half2_rn(acc[rl * 64 + ch2 * 2], acc[rl * 64 + ch2 * 2 + 1]);
        ((__half2*)(out + (size_t)n * 64))[ch2] = v;
    }
}

// ---------- prop32_b: block = 128 nodes; 16 lanes/edge (2 ch, 4B gather) ----------
// LDS stride 36 mixes 4*rloc into bank index (breaks the 4-way even-bank alias).
// Fused add-input; fp16 (Q) or fp32 (final out) epilogue.
template <bool F32OUT>
__global__ __launch_bounds__(256) void prop32_b(const __half* __restrict__ t,
                                                const int* __restrict__ rowptr,
                                                const int2* __restrict__ colw,
                                                const void* __restrict__ addin,
                                                void* __restrict__ outv, int nnodes) {
    __shared__ float acc[128 * 36];   // 18 KB
    const int tid = threadIdx.x;
    const int n0 = blockIdx.x * 128;
    const int nend = min(n0 + 128, nnodes);
    for (int i = tid; i < 128 * 36; i += 256) acc[i] = 0.f;
    __syncthreads();
    const int es = rowptr[n0];
    const int ee = rowptr[nend];
    const int off = n0 & 128;
    const int cq = tid & 15;          // channel pair: ch 2*cq, 2*cq+1
    for (int e = es + (tid >> 4); e < ee; e += 16) {
        int2 cw = colw[e];
        int c = cw.x & 0xFFFFF;
        int rloc = (cw.x >> 20) - off;
        float w = __int_as_float(cw.y);
        __half2 r = ((const __half2*)(t + (size_t)c * 32))[cq];
        float2 f = __half22float2(r);
        float* ap = acc + rloc * 36 + cq * 2;
        atomicAdd(ap + 0, w * f.x);
        atomicAdd(ap + 1, w * f.y);
    }
    __syncthreads();
    for (int i = tid; i < 128 * 16; i += 256) {   // 128 rows x 16 ch-pairs
        int rl = i >> 4;
        int n = n0 + rl;
        if (n >= nnodes) break;
        int ch2 = i & 15;
        float a0 = acc[rl * 36 + ch2 * 2];
        float a1 = acc[rl * 36 + ch2 * 2 + 1];
        if (F32OUT) {
            const float* add = (const float*)addin;
            float* out = (float*)outv;
            float2 av = ((const float2*)(add + (size_t)n * 32))[ch2];
            ((float2*)(out + (size_t)n * 32))[ch2] = make_float2(av.x + a0, av.y + a1);
        } else {
            const __half* add = (const __half*)addin;
            __half* out = (__half*)outv;
            float2 av = __half22float2(((const __half2*)(add + (size_t)n * 32))[ch2]);
            ((__half2*)(out + (size_t)n * 32))[ch2] = __floats2half2_rn(a0 + av.x, a1 + av.y);
        }
    }
}

// ---------- layer-1 MFMA GEMM: Hh = relu([xh|T1h|T2h] @ W1f + b1), fp16 out ----------
__global__ __launch_bounds__(256) void gemm_l1_mfma(const __half* __restrict__ A0,
                                                    const __half* __restrict__ A1,
                                                    const __half* __restrict__ A2,
                                                    const __half* __restrict__ Wf,
                                                    const float* __restrict__ b1,
                                                    __half* __restrict__ Hh, int nnodes) {
    const int wave = threadIdx.x >> 6;
    const int lane = threadIdx.x & 63;
    const int node0 = blockIdx.x * 64 + wave * 16;
    const int m = lane & 15;
    const int quad = lane >> 4;
    int arow = node0 + m;
    if (arow >= nnodes) arow = nnodes - 1;   // clamp: garbage rows never stored
    const __half* Ap[3] = {A0, A1, A2};
    f16x8 a[6];
#pragma unroll
    for (int kh = 0; kh < 6; ++kh) {
        const __half* A = Ap[kh >> 1];
        a[kh] = *(const f16x8*)(A + (size_t)arow * 64 + ((kh & 1) << 5) + (quad << 3));
    }
#pragma unroll
    for (int ct = 0; ct < 4; ++ct) {
        f32x4 acc = {0.f, 0.f, 0.f, 0.f};
#pragma unroll
        for (int kh = 0; kh < 6; ++kh) {
            f16x8 b = *(const f16x8*)(Wf + ((size_t)(ct * 6 + kh) * 64 + lane) * 8);
            acc = __builtin_amdgcn_mfma_f32_16x16x32_f16(a[kh], b, acc, 0, 0, 0);
        }
        int col = (ct << 4) | m;
        float bias = b1[col];
#pragma unroll
        for (int r = 0; r < 4; ++r) {
            int n = node0 + (quad << 2) + r;
            if (n < nnodes) Hh[(size_t)n * 64 + col] = __float2half(fmaxf(acc[r] + bias, 0.f));
        }
    }
}

// ---------- layer-2 MFMA GEMM: [P0|G1|G2] = Hh @ W2f (+b2 on P0) ----------
__global__ __launch_bounds__(256) void gemm_l2_mfma(const __half* __restrict__ Hh,
                                                    const __half* __restrict__ Wf,
                                                    const float* __restrict__ b2,
                                                    float* __restrict__ P0,
                                                    __half* __restrict__ G1,
                                                    __half* __restrict__ G2, int nnodes) {
    const int wave = threadIdx.x >> 6;
    const int lane = threadIdx.x & 63;
    const int node0 = blockIdx.x * 64 + wave * 16;
    const int m = lane & 15;
    const int quad = lane >> 4;
    int arow = node0 + m;
    if (arow >= nnodes) arow = nnodes - 1;
    f16x8 a0 = *(const f16x8*)(Hh + (size_t)arow * 64 + (quad << 3));
    f16x8 a1 = *(const f16x8*)(Hh + (size_t)arow * 64 + 32 + (quad << 3));
#pragma unroll
    for (int ct = 0; ct < 6; ++ct) {
        f32x4 acc = {0.f, 0.f, 0.f, 0.f};
        f16x8 b0 = *(const f16x8*)(Wf + ((size_t)(ct * 2 + 0) * 64 + lane) * 8);
        f16x8 b1v = *(const f16x8*)(Wf + ((size_t)(ct * 2 + 1) * 64 + lane) * 8);
        acc = __builtin_amdgcn_mfma_f32_16x16x32_f16(a0, b0, acc, 0, 0, 0);
        acc = __builtin_amdgcn_mfma_f32_16x16x32_f16(a1, b1v, acc, 0, 0, 0);
        int seg = ct >> 1;                      // wave-uniform
        int c = ((ct & 1) << 4) | m;            // col within segment
#pragma unroll
        for (int r = 0; r < 4; ++r) {
            int n = node0 + (quad << 2) + r;
            if (n >= nnodes) continue;
            float v = acc[r];
            if (seg == 0)      P0[(size_t)n * 32 + c] = v + b2[c];
            else if (seg == 1) G1[(size_t)n * 32 + c] = __float2half(v);
            else               G2[(size_t)n * 32 + c] = __float2half(v);
        }
    }
}

extern "C" void kernel_launch(void* const* d_in, const int* in_sizes, int n_in,
                              void* d_out, int out_size, void* d_ws, size_t ws_size,
                              hipStream_t stream) {
    const float* x  = (const float*)d_in[0];
    const int*   ei = (const int*)d_in[1];
    const float* W1 = (const float*)d_in[2];
    const float* b1 = (const float*)d_in[3];
    const float* W2 = (const float*)d_in[4];
    const float* b2 = (const float*)d_in[5];
    float* out = (float*)d_out;

    const int NN = N_NODES_C;
    const int NE = N_EDGES_C;
    const size_t HFEAT_BYTES = (size_t)NN * 64 * sizeof(__half);
    const size_t H32_BYTES = (size_t)NN * 32 * sizeof(__half);

    char* ws = (char*)d_ws;
    size_t off = 0;
    auto alloc = [&](size_t bytes) -> void* {
        void* p = ws + off;
        off += (bytes + 255) & ~(size_t)255;
        return p;
    };
    int*    bucket_cnt  = (int*)alloc((size_t)NBUK * 4);
    int*    bucket_base = (int*)alloc((size_t)(NBUK + 1) * 4);
    int*    bucket_next = (int*)alloc((size_t)NBUK * 4);
    int*    rowptr      = (int*)alloc((size_t)(NN + 1) * 4);
    float*  dis         = (float*)alloc((size_t)NN * 4);
    int2*   staged      = (int2*)alloc((size_t)NE * 8);
    int2*   colw        = (int2*)alloc((size_t)NE * 8);
    __half* xh          = (__half*)alloc(HFEAT_BYTES);
    __half* T1h         = (__half*)alloc(HFEAT_BYTES);   // layer1: T1; layer2: G1
    __half* T2h         = (__half*)alloc(HFEAT_BYTES);   // layer1: T2; layer2: G2
    __half* Hh          = (__half*)alloc(HFEAT_BYTES);
    __half* Qh          = (__half*)alloc(H32_BYTES);
    float*  P0          = (float*)alloc((size_t)NN * 32 * 4);
    __half* W1f         = (__half*)alloc((size_t)4 * 6 * 64 * 8 * 2);   // 24 KB
    __half* W2f         = (__half*)alloc((size_t)6 * 2 * 64 * 8 * 2);   // 12 KB

    const int CONVB = (NN * 64 / 4 + 255) / 256;
    const int BINB = (NE + CHUNK - 1) / CHUNK;
    const int GEMMB = (NN + 63) / 64;
    const int PROPB = (NN + 127) / 128;   // 782 blocks, 128 nodes each

    // ---- CSR build (bucket-atomic) + weight packing + x->fp16 ----
    hipMemsetAsync(bucket_cnt, 0, (size_t)NBUK * 4, stream);
    bucket_hist<<<BINB, 256, 0, stream>>>(ei, bucket_cnt, NE);
    bucket_scan<<<1, 64, 0, stream>>>(bucket_cnt, bucket_base, bucket_next, NBUK);
    bin_stage<<<BINB, 256, 0, stream>>>(ei, bucket_next, staged, NE);
    bin_count<<<NBUK, 256, 0, stream>>>(staged, bucket_base, rowptr, dis, NN, NE);
    bin_place<<<NBUK, 256, 0, stream>>>(staged, rowptr, dis, colw, NN);
    fold_w1f<<<(12288 + 255) / 256, 256, 0, stream>>>(W1, W1f);
    fold_w2f<<<(6144 + 255) / 256, 256, 0, stream>>>(W2, W2f);
    f2h_kernel<<<CONVB, 256, 0, stream>>>(x, xh, NN * 64 / 4);

    // ---- layer 1: Hh = relu(x@(W0-W2) + T1@W1 + T2@(2W2) + b1), T2 = prop(T1) ----
    prop64_b<<<PROPB, 256, 0, stream>>>(xh, rowptr, colw, T1h, NN);
    prop64_b<<<PROPB, 256, 0, stream>>>(T1h, rowptr, colw, T2h, NN);
    gemm_l1_mfma<<<GEMMB, 256, 0, stream>>>(xh, T1h, T2h, W1f, b1, Hh, NN);

    // ---- layer 2 (factored): out = P0 + prop(G1 + prop(G2)) ----
    gemm_l2_mfma<<<GEMMB, 256, 0, stream>>>(Hh, W2f, b2, P0, T1h, T2h, NN);
    prop32_b<false><<<PROPB, 256, 0, stream>>>(T2h, rowptr, colw, T1h, Qh, NN);
    prop32_b<true><<<PROPB, 256, 0, stream>>>(Qh, rowptr, colw, P0, out, NN);
}

// Round 15
// 313.354 us; speedup vs baseline: 5.4336x; 5.4336x over previous
//
#include <hip/hip_runtime.h>
#include <hip/hip_fp16.h>

#define N_NODES_C 100000
#define N_EDGES_C 1200000
#define NBUK ((N_NODES_C + 255) >> 8)   // 391 buckets of 256 nodes
#define CHUNK 4096                       // edges per binning block

typedef _Float16 f16x8 __attribute__((ext_vector_type(8)));
typedef float f32x4 __attribute__((ext_vector_type(4)));

// ---------- bucket-level histogram: LDS aggregate, ~115k global atomics ----------
__global__ __launch_bounds__(256) void bucket_hist(const int* __restrict__ ei,
                                                   int* __restrict__ bucket_cnt, int nedges) {
    __shared__ int cnt[NBUK];
    const int tid = threadIdx.x;
    const int base = blockIdx.x * CHUNK;
    const int nloc = min(CHUNK, nedges - base);
    for (int i = tid; i < NBUK; i += 256) cnt[i] = 0;
    __syncthreads();
    for (int i = tid; i < nloc; i += 256) atomicAdd(&cnt[ei[base + i] >> 8], 1);
    __syncthreads();
    for (int b = tid; b < NBUK; b += 256) {
        int n = cnt[b];
        if (n) atomicAdd(&bucket_cnt[b], n);
    }
}

// ---------- scan 391 bucket counts -> bucket_base / bucket_next ----------
__global__ void bucket_scan(const int* __restrict__ bucket_cnt, int* __restrict__ bucket_base,
                            int* __restrict__ bucket_next, int nb) {
    if (threadIdx.x == 0 && blockIdx.x == 0) {
        int acc = 0;
        for (int i = 0; i < nb; ++i) {
            bucket_base[i] = acc;
            bucket_next[i] = acc;
            acc += bucket_cnt[i];
        }
        bucket_base[nb] = acc;
    }
}

// ---------- phase B: LDS-binned staging of (r,c) grouped by 256-node bucket ----------
__global__ __launch_bounds__(256) void bin_stage(const int* __restrict__ ei,
                                                 int* __restrict__ bucket_next,
                                                 int2* __restrict__ staged, int nedges) {
    __shared__ int cnt[NBUK];
    __shared__ int ofs[NBUK];
    __shared__ int run[NBUK];
    __shared__ int gbase[NBUK];
    __shared__ int ssum[256];
    __shared__ int2 sedge[CHUNK];
    const int tid = threadIdx.x;
    const int base = blockIdx.x * CHUNK;
    const int nloc = min(CHUNK, nedges - base);

    for (int i = tid; i < NBUK; i += 256) { cnt[i] = 0; run[i] = 0; }
    __syncthreads();

    int r[16], c[16];
#pragma unroll
    for (int k = 0; k < 16; ++k) {
        int loc = tid + k * 256;
        bool ok = loc < nloc;
        int idx = base + loc;
        r[k] = ok ? ei[idx] : -1;
        c[k] = ok ? ei[nedges + idx] : 0;
        if (ok) atomicAdd(&cnt[r[k] >> 8], 1);
    }
    __syncthreads();

    // exclusive scan of cnt[NBUK] -> ofs
    int a0 = (2 * tid < NBUK) ? cnt[2 * tid] : 0;
    int a1 = (2 * tid + 1 < NBUK) ? cnt[2 * tid + 1] : 0;
    ssum[tid] = a0 + a1;
    __syncthreads();
    for (int off = 1; off < 256; off <<= 1) {
        int v = ssum[tid];
        int add = (tid >= off) ? ssum[tid - off] : 0;
        __syncthreads();
        ssum[tid] = v + add;
        __syncthreads();
    }
    int excl = (tid > 0) ? ssum[tid - 1] : 0;
    if (2 * tid < NBUK) ofs[2 * tid] = excl;
    if (2 * tid + 1 < NBUK) ofs[2 * tid + 1] = excl + a0;
    __syncthreads();

    // place edges into LDS grouped by bucket
#pragma unroll
    for (int k = 0; k < 16; ++k) {
        if (r[k] >= 0) {
            int b = r[k] >> 8;
            int p = atomicAdd(&run[b], 1);
            sedge[ofs[b] + p] = make_int2(r[k], c[k]);
        }
    }
    __syncthreads();

    // allocate global runs (one atomic per non-empty bucket)
    for (int b = tid; b < NBUK; b += 256) {
        int n = cnt[b];
        gbase[b] = n ? atomicAdd(&bucket_next[b], n) : 0;
    }
    __syncthreads();

    // coalesced copy-out: consecutive i are bucket-grouped runs
    for (int i = tid; i < nloc; i += 256) {
        int2 e = sedge[i];
        int b = e.x >> 8;
        staged[gbase[b] + (i - ofs[b])] = e;
    }
}

// ---------- phase C1: per-bucket degree count -> rowptr slice + deg_inv_sqrt ----------
__global__ __launch_bounds__(256) void bin_count(const int2* __restrict__ staged,
                                                 const int* __restrict__ bucket_base,
                                                 int* __restrict__ rowptr, float* __restrict__ dis,
                                                 int nnodes, int nedges) {
    __shared__ int deg[256];
    __shared__ int ssum[256];
    const int b = blockIdx.x;
    const int n0 = b << 8;
    const int nend = min(n0 + 256, nnodes);
    const int nloc = nend - n0;
    const int tid = threadIdx.x;
    deg[tid] = 0;
    __syncthreads();
    const int ebase = bucket_base[b];
    const int ecount = bucket_base[b + 1] - ebase;
    for (int i = tid; i < ecount; i += 256) {
        atomicAdd(&deg[staged[ebase + i].x - n0], 1);
    }
    __syncthreads();
    int d = deg[tid];
    if (tid < nloc) {
        float df = (float)d;
        dis[n0 + tid] = (d > 0) ? (1.0f / sqrtf(fmaxf(df, 1.f))) : 0.f;
    }
    ssum[tid] = d;
    __syncthreads();
    for (int off = 1; off < 256; off <<= 1) {
        int v = ssum[tid];
        int add = (tid >= off) ? ssum[tid - off] : 0;
        __syncthreads();
        ssum[tid] = v + add;
        __syncthreads();
    }
    int excl = (tid > 0) ? ssum[tid - 1] : 0;
    if (tid < nloc) rowptr[n0 + tid] = ebase + excl;
    if (b == NBUK - 1 && tid == 0) rowptr[nnodes] = nedges;
}

// ---------- phase C2: per-bucket exact CSR placement + norm weight ----------
__global__ __launch_bounds__(256) void bin_place(const int2* __restrict__ staged,
                                                 const int* __restrict__ rowptr,
                                                 const float* __restrict__ dis,
                                                 int2* __restrict__ colw, int nnodes) {
    __shared__ int rp[256];
    __shared__ int nx[256];
    __shared__ float dl[256];
    const int b = blockIdx.x;
    const int n0 = b << 8;
    const int nend = min(n0 + 256, nnodes);
    const int nloc = nend - n0;
    const int tid = threadIdx.x;
    if (tid < nloc) {
        rp[tid] = rowptr[n0 + tid];
        dl[tid] = dis[n0 + tid];
    }
    nx[tid] = 0;
    __syncthreads();
    const int ebase = rowptr[n0];
    const int ecount = rowptr[nend] - ebase;
    for (int i = tid; i < ecount; i += 256) {
        int2 e = staged[ebase + i];
        int rrel = e.x - n0;
        int p = atomicAdd(&nx[rrel], 1);
        float w = -dl[rrel] * dis[e.y];
        colw[rp[rrel] + p] = make_int2(e.y, __float_as_int(w));
    }
}

// ---------- pack layer-1 folded weights into MFMA B-fragment layout (fp16) ----------
__global__ void fold_w1f(const float* __restrict__ W, __half* __restrict__ Wf) {
    int i = blockIdx.x * blockDim.x + threadIdx.x;
    if (i >= 4 * 6 * 64 * 8) return;
    int j = i & 7;
    int lane = (i >> 3) & 63;
    int rest = i >> 9;
    int kh = rest % 6;
    int ct = rest / 6;
    int term = kh >> 1;
    int k = ((kh & 1) << 5) | ((lane >> 4) << 3) | j;
    int c = (ct << 4) | (lane & 15);
    float w0 = W[k * 64 + c];
    float w1 = W[4096 + k * 64 + c];
    float w2 = W[2 * 4096 + k * 64 + c];
    float v = (term == 0) ? (w0 - w2) : ((term == 1) ? w1 : 2.0f * w2);
    Wf[i] = __float2half(v);
}

// ---------- pack layer-2 concat weights into MFMA B-fragment layout (fp16) ----------
__global__ void fold_w2f(const float* __restrict__ W, __half* __restrict__ Wf) {
    int i = blockIdx.x * blockDim.x + threadIdx.x;
    if (i >= 6 * 2 * 64 * 8) return;
    int j = i & 7;
    int lane = (i >> 3) & 63;
    int rest = i >> 9;
    int kh = rest & 1;
    int ct = rest >> 1;
    int k = (kh << 5) | ((lane >> 4) << 3) | j;
    int cg = ct * 16 + (lane & 15);
    int seg = cg >> 5;
    int c = cg & 31;
    float w0 = W[k * 32 + c];
    float w1 = W[2048 + k * 32 + c];
    float w2 = W[2 * 2048 + k * 32 + c];
    float v = (seg == 0) ? (w0 - w2) : ((seg == 1) ? w1 : 2.0f * w2);
    Wf[i] = __float2half(v);
}

// ---------- fp32 -> fp16 feature conversion (4 elems/thread) ----------
__global__ void f2h_kernel(const float* __restrict__ in, __half* __restrict__ out, int n4) {
    int i = blockIdx.x * blockDim.x + threadIdx.x;
    if (i >= n4) return;
    float4 v = ((const float4*)in)[i];
    __half2 tmp[2];
    tmp[0] = __floats2half2_rn(v.x, v.y);
    tmp[1] = __floats2half2_rn(v.z, v.w);
    ((float2*)out)[i] = *(float2*)tmp;
}

// ---------- prop64: 16 lanes/edge (4 ch, 8B loads), 4 edges/instr ----------
// accs=4, reduce = 2 shfl rounds; dual-gather main + wave-uniform single tail.
__global__ __launch_bounds__(256) void prop_gather_h(const __half* __restrict__ t,
                                                     const int* __restrict__ rowptr,
                                                     const int2* __restrict__ colw,
                                                     __half* __restrict__ out, int nnodes) {
    int node = blockIdx.x * 4 + (threadIdx.x >> 6);
    if (node >= nnodes) return;
    int lane = threadIdx.x & 63;
    int g = lane >> 4;     // edge group 0..3
    int cq = lane & 15;    // channel quad: ch 4*cq .. 4*cq+3
    int s = rowptr[node];
    int e = rowptr[node + 1];
    float acc[4] = {0.f, 0.f, 0.f, 0.f};
    for (int base = s; base < e; base += 64) {
        int m = e - base;
        if (m > 64) m = 64;
        int2 cw = (lane < m) ? colw[base + lane] : make_int2(0, 0);
        int iters = (m + 3) >> 2;
        int it = 0;
        for (; it + 1 < iters; it += 2) {
            int j0 = (it << 2) | g;
            int j1 = j0 + 4;
            int c0 = __shfl(cw.x, j0);
            float w0 = __int_as_float(__shfl(cw.y, j0));
            int c1 = __shfl(cw.x, j1);
            float w1 = __int_as_float(__shfl(cw.y, j1));
            float2 raw0 = ((const float2*)(t + (size_t)c0 * 64))[cq];
            float2 raw1 = ((const float2*)(t + (size_t)c1 * 64))[cq];
            const __half2* h0 = (const __half2*)&raw0;
            const __half2* h1 = (const __half2*)&raw1;
            float2 f00 = __half22float2(h0[0]);
            float2 f01 = __half22float2(h0[1]);
            float2 f10 = __half22float2(h1[0]);
            float2 f11 = __half22float2(h1[1]);
            acc[0] += w0 * f00.x + w1 * f10.x;
            acc[1] += w0 * f00.y + w1 * f10.y;
            acc[2] += w0 * f01.x + w1 * f11.x;
            acc[3] += w0 * f01.y + w1 * f11.y;
        }
        if (it < iters) {   // wave-uniform tail (sentinel-safe)
            int j0 = (it << 2) | g;
            int c0 = __shfl(cw.x, j0);
            float w0 = __int_as_float(__shfl(cw.y, j0));
            float2 raw0 = ((const float2*)(t + (size_t)c0 * 64))[cq];
            const __half2* h0 = (const __half2*)&raw0;
            float2 f00 = __half22float2(h0[0]);
            float2 f01 = __half22float2(h0[1]);
            acc[0] += w0 * f00.x;
            acc[1] += w0 * f00.y;
            acc[2] += w0 * f01.x;
            acc[3] += w0 * f01.y;
        }
    }
#pragma unroll
    for (int i = 0; i < 4; ++i) {
        acc[i] += __shfl_xor(acc[i], 16);
        acc[i] += __shfl_xor(acc[i], 32);
    }
    if (g == 0) {
        __half2 tmp[2];
        tmp[0] = __floats2half2_rn(acc[0], acc[1]);
        tmp[1] = __floats2half2_rn(acc[2], acc[3]);
        ((float2*)(out + (size_t)node * 64))[cq] = *(float2*)tmp;
    }
}

// ---------- prop32: 16 lanes/edge (2 ch, 4B loads), 4 edges/instr ----------
// accs=2, reduce = 2 shfl rounds x 2; fused add-input; fp16/fp32 out.
template <bool F32OUT>
__global__ __launch_bounds__(256) void prop_gather32(const __half* __restrict__ t,
                                                     const int* __restrict__ rowptr,
                                                     const int2* __restrict__ colw,
                                                     const void* __restrict__ addin,
                                                     void* __restrict__ outv, int nnodes) {
    int node = blockIdx.x * 4 + (threadIdx.x >> 6);
    if (node >= nnodes) return;
    int lane = threadIdx.x & 63;
    int g = lane >> 4;     // edge group 0..3
    int cq = lane & 15;    // channel pair: ch 2*cq, 2*cq+1
    int s = rowptr[node];
    int e = rowptr[node + 1];
    float acc0 = 0.f, acc1 = 0.f;
    for (int base = s; base < e; base += 64) {
        int m = e - base;
        if (m > 64) m = 64;
        int2 cw = (lane < m) ? colw[base + lane] : make_int2(0, 0);
        int iters = (m + 3) >> 2;
        int it = 0;
        for (; it + 1 < iters; it += 2) {
            int j0 = (it << 2) | g;
            int j1 = j0 + 4;
            int c0 = __shfl(cw.x, j0);
            float w0 = __int_as_float(__shfl(cw.y, j0));
            int c1 = __shfl(cw.x, j1);
            float w1 = __int_as_float(__shfl(cw.y, j1));
            __half2 r0 = ((const __half2*)(t + (size_t)c0 * 32))[cq];
            __half2 r1 = ((const __half2*)(t + (size_t)c1 * 32))[cq];
            float2 f0 = __half22float2(r0);
            float2 f1 = __half22float2(r1);
            acc0 += w0 * f0.x + w1 * f1.x;
            acc1 += w0 * f0.y + w1 * f1.y;
        }
        if (it < iters) {   // wave-uniform tail (sentinel-safe)
            int j0 = (it << 2) | g;
            int c0 = __shfl(cw.x, j0);
            float w0 = __int_as_float(__shfl(cw.y, j0));
            __half2 r0 = ((const __half2*)(t + (size_t)c0 * 32))[cq];
            float2 f0 = __half22float2(r0);
            acc0 += w0 * f0.x;
            acc1 += w0 * f0.y;
        }
    }
    acc0 += __shfl_xor(acc0, 16); acc1 += __shfl_xor(acc1, 16);
    acc0 += __shfl_xor(acc0, 32); acc1 += __shfl_xor(acc1, 32);
    if (g == 0) {
        if (F32OUT) {
            const float* add = (const float*)addin;
            float* out = (float*)outv;
            float2 a = ((const float2*)(add + (size_t)node * 32))[cq];
            a.x += acc0;
            a.y += acc1;
            ((float2*)(out + (size_t)node * 32))[cq] = a;
        } else {
            const __half* add = (const __half*)addin;
            __half* out = (__half*)outv;
            float2 af = __half22float2(((const __half2*)(add + (size_t)node * 32))[cq]);
            ((__half2*)(out + (size_t)node * 32))[cq] = __floats2half2_rn(acc0 + af.x, acc1 + af.y);
        }
    }
}

// ---------- layer-1 MFMA GEMM: Hh = relu([xh|T1h|T2h] @ W1f + b1), fp16 out ----------
__global__ __launch_bounds__(256) void gemm_l1_mfma(const __half* __restrict__ A0,
                                                    const __half* __restrict__ A1,
                                                    const __half* __restrict__ A2,
                                                    const __half* __restrict__ Wf,
                                                    const float* __restrict__ b1,
                                                    __half* __restrict__ Hh, int nnodes) {
    const int wave = threadIdx.x >> 6;
    const int lane = threadIdx.x & 63;
    const int node0 = blockIdx.x * 64 + wave * 16;
    const int m = lane & 15;
    const int quad = lane >> 4;
    int arow = node0 + m;
    if (arow >= nnodes) arow = nnodes - 1;   // clamp: garbage rows never stored
    const __half* Ap[3] = {A0, A1, A2};
    f16x8 a[6];
#pragma unroll
    for (int kh = 0; kh < 6; ++kh) {
        const __half* A = Ap[kh >> 1];
        a[kh] = *(const f16x8*)(A + (size_t)arow * 64 + ((kh & 1) << 5) + (quad << 3));
    }
#pragma unroll
    for (int ct = 0; ct < 4; ++ct) {
        f32x4 acc = {0.f, 0.f, 0.f, 0.f};
#pragma unroll
        for (int kh = 0; kh < 6; ++kh) {
            f16x8 b = *(const f16x8*)(Wf + ((size_t)(ct * 6 + kh) * 64 + lane) * 8);
            acc = __builtin_amdgcn_mfma_f32_16x16x32_f16(a[kh], b, acc, 0, 0, 0);
        }
        int col = (ct << 4) | m;
        float bias = b1[col];
#pragma unroll
        for (int r = 0; r < 4; ++r) {
            int n = node0 + (quad << 2) + r;
            if (n < nnodes) Hh[(size_t)n * 64 + col] = __float2half(fmaxf(acc[r] + bias, 0.f));
        }
    }
}

// ---------- layer-2 MFMA GEMM: [P0|G1|G2] = Hh @ W2f (+b2 on P0) ----------
__global__ __launch_bounds__(256) void gemm_l2_mfma(const __half* __restrict__ Hh,
                                                    const __half* __restrict__ Wf,
                                                    const float* __restrict__ b2,
                                                    float* __restrict__ P0,
                                                    __half* __restrict__ G1,
                                                    __half* __restrict__ G2, int nnodes) {
    const int wave = threadIdx.x >> 6;
    const int lane = threadIdx.x & 63;
    const int node0 = blockIdx.x * 64 + wave * 16;
    const int m = lane & 15;
    const int quad = lane >> 4;
    int arow = node0 + m;
    if (arow >= nnodes) arow = nnodes - 1;
    f16x8 a0 = *(const f16x8*)(Hh + (size_t)arow * 64 + (quad << 3));
    f16x8 a1 = *(const f16x8*)(Hh + (size_t)arow * 64 + 32 + (quad << 3));
#pragma unroll
    for (int ct = 0; ct < 6; ++ct) {
        f32x4 acc = {0.f, 0.f, 0.f, 0.f};
        f16x8 b0 = *(const f16x8*)(Wf + ((size_t)(ct * 2 + 0) * 64 + lane) * 8);
        f16x8 b1v = *(const f16x8*)(Wf + ((size_t)(ct * 2 + 1) * 64 + lane) * 8);
        acc = __builtin_amdgcn_mfma_f32_16x16x32_f16(a0, b0, acc, 0, 0, 0);
        acc = __builtin_amdgcn_mfma_f32_16x16x32_f16(a1, b1v, acc, 0, 0, 0);
        int seg = ct >> 1;                      // wave-uniform
        int c = ((ct & 1) << 4) | m;            // col within segment
#pragma unroll
        for (int r = 0; r < 4; ++r) {
            int n = node0 + (quad << 2) + r;
            if (n >= nnodes) continue;
            float v = acc[r];
            if (seg == 0)      P0[(size_t)n * 32 + c] = v + b2[c];
            else if (seg == 1) G1[(size_t)n * 32 + c] = __float2half(v);
            else               G2[(size_t)n * 32 + c] = __float2half(v);
        }
    }
}

extern "C" void kernel_launch(void* const* d_in, const int* in_sizes, int n_in,
                              void* d_out, int out_size, void* d_ws, size_t ws_size,
                              hipStream_t stream) {
    const float* x  = (const float*)d_in[0];
    const int*   ei = (const int*)d_in[1];
    const float* W1 = (const float*)d_in[2];
    const float* b1 = (const float*)d_in[3];
    const float* W2 = (const float*)d_in[4];
    const float* b2 = (const float*)d_in[5];
    float* out = (float*)d_out;

    const int NN = N_NODES_C;
    const int NE = N_EDGES_C;
    const size_t HFEAT_BYTES = (size_t)NN * 64 * sizeof(__half);
    const size_t H32_BYTES = (size_t)NN * 32 * sizeof(__half);

    char* ws = (char*)d_ws;
    size_t off = 0;
    auto alloc = [&](size_t bytes) -> void* {
        void* p = ws + off;
        off += (bytes + 255) & ~(size_t)255;
        return p;
    };
    int*    bucket_cnt  = (int*)alloc((size_t)NBUK * 4);
    int*    bucket_base = (int*)alloc((size_t)(NBUK + 1) * 4);
    int*    bucket_next = (int*)alloc((size_t)NBUK * 4);
    int*    rowptr      = (int*)alloc((size_t)(NN + 1) * 4);
    float*  dis         = (float*)alloc((size_t)NN * 4);
    int2*   staged      = (int2*)alloc((size_t)NE * 8);
    int2*   colw        = (int2*)alloc((size_t)NE * 8);
    __half* xh          = (__half*)alloc(HFEAT_BYTES);
    __half* T1h         = (__half*)alloc(HFEAT_BYTES);   // layer1: T1; layer2: G1
    __half* T2h         = (__half*)alloc(HFEAT_BYTES);   // layer1: T2; layer2: G2
    __half* Hh          = (__half*)alloc(HFEAT_BYTES);
    __half* Qh          = (__half*)alloc(H32_BYTES);
    float*  P0          = (float*)alloc((size_t)NN * 32 * 4);
    __half* W1f         = (__half*)alloc((size_t)4 * 6 * 64 * 8 * 2);   // 24 KB
    __half* W2f         = (__half*)alloc((size_t)6 * 2 * 64 * 8 * 2);   // 12 KB

    const int PROPB = (NN + 3) / 4;
    const int CONVB = (NN * 64 / 4 + 255) / 256;
    const int BINB = (NE + CHUNK - 1) / CHUNK;
    const int GEMMB = (NN + 63) / 64;

    // ---- CSR build (bucket-atomic) + weight packing + x->fp16 ----
    hipMemsetAsync(bucket_cnt, 0, (size_t)NBUK * 4, stream);
    bucket_hist<<<BINB, 256, 0, stream>>>(ei, bucket_cnt, NE);
    bucket_scan<<<1, 64, 0, stream>>>(bucket_cnt, bucket_base, bucket_next, NBUK);
    bin_stage<<<BINB, 256, 0, stream>>>(ei, bucket_next, staged, NE);
    bin_count<<<NBUK, 256, 0, stream>>>(staged, bucket_base, rowptr, dis, NN, NE);
    bin_place<<<NBUK, 256, 0, stream>>>(staged, rowptr, dis, colw, NN);
    fold_w1f<<<(12288 + 255) / 256, 256, 0, stream>>>(W1, W1f);
    fold_w2f<<<(6144 + 255) / 256, 256, 0, stream>>>(W2, W2f);
    f2h_kernel<<<CONVB, 256, 0, stream>>>(x, xh, NN * 64 / 4);

    // ---- layer 1: Hh = relu(x@(W0-W2) + T1@W1 + T2@(2W2) + b1), T2 = prop(T1) ----
    prop_gather_h<<<PROPB, 256, 0, stream>>>(xh, rowptr, colw, T1h, NN);
    prop_gather_h<<<PROPB, 256, 0, stream>>>(T1h, rowptr, colw, T2h, NN);
    gemm_l1_mfma<<<GEMMB, 256, 0, stream>>>(xh, T1h, T2h, W1f, b1, Hh, NN);

    // ---- layer 2 (factored): out = P0 + prop(G1 + prop(G2)) ----
    gemm_l2_mfma<<<GEMMB, 256, 0, stream>>>(Hh, W2f, b2, P0, T1h, T2h, NN);
    prop_gather32<false><<<PROPB, 256, 0, stream>>>(T2h, rowptr, colw, T1h, Qh, NN);
    prop_gather32<true><<<PROPB, 256, 0, stream>>>(Qh, rowptr, colw, P0, out, NN);
}

// Round 16
// 285.257 us; speedup vs baseline: 5.9688x; 1.0985x over previous
//
#include <hip/hip_runtime.h>
#include <hip/hip_fp16.h>

#define N_NODES_C 100000
#define N_EDGES_C 1200000
#define NBUK ((N_NODES_C + 255) >> 8)   // 391 buckets of 256 nodes
#define CHUNK 4096                       // edges per binning block

typedef _Float16 f16x8 __attribute__((ext_vector_type(8)));
typedef float f32x4 __attribute__((ext_vector_type(4)));

// ---------- merged: bucket histogram (blocks 0..histB-1) + fp32->fp16 convert ----------
__global__ __launch_bounds__(256) void hist_f2h(const int* __restrict__ ei,
                                                int* __restrict__ bucket_cnt,
                                                const float* __restrict__ x,
                                                __half* __restrict__ xh,
                                                int nedges, int n4, int histB) {
    __shared__ int cnt[NBUK];
    const int tid = threadIdx.x;
    if (blockIdx.x < histB) {
        const int base = blockIdx.x * CHUNK;
        const int nloc = min(CHUNK, nedges - base);
        for (int i = tid; i < NBUK; i += 256) cnt[i] = 0;
        __syncthreads();
        for (int i = tid; i < nloc; i += 256) atomicAdd(&cnt[ei[base + i] >> 8], 1);
        __syncthreads();
        for (int b = tid; b < NBUK; b += 256) {
            int n = cnt[b];
            if (n) atomicAdd(&bucket_cnt[b], n);
        }
    } else {
        int i = (blockIdx.x - histB) * 256 + tid;
        if (i < n4) {
            float4 v = ((const float4*)x)[i];
            __half2 tmp[2];
            tmp[0] = __floats2half2_rn(v.x, v.y);
            tmp[1] = __floats2half2_rn(v.z, v.w);
            ((float2*)xh)[i] = *(float2*)tmp;
        }
    }
}

// ---------- parallel scan of 391 bucket counts -> bucket_base / bucket_next ----------
__global__ __launch_bounds__(256) void bucket_scan(const int* __restrict__ bucket_cnt,
                                                   int* __restrict__ bucket_base,
                                                   int* __restrict__ bucket_next, int nb) {
    __shared__ int s[256];
    const int tid = threadIdx.x;
    int a0 = (2 * tid < nb) ? bucket_cnt[2 * tid] : 0;
    int a1 = (2 * tid + 1 < nb) ? bucket_cnt[2 * tid + 1] : 0;
    s[tid] = a0 + a1;
    __syncthreads();
    for (int off = 1; off < 256; off <<= 1) {
        int v = s[tid];
        int add = (tid >= off) ? s[tid - off] : 0;
        __syncthreads();
        s[tid] = v + add;
        __syncthreads();
    }
    int excl = (tid > 0) ? s[tid - 1] : 0;
    if (2 * tid < nb) { bucket_base[2 * tid] = excl; bucket_next[2 * tid] = excl; }
    if (2 * tid + 1 < nb) { bucket_base[2 * tid + 1] = excl + a0; bucket_next[2 * tid + 1] = excl + a0; }
    if (tid == 255) bucket_base[nb] = s[255];
}

// ---------- phase B: LDS-binned staging of (r,c) grouped by 256-node bucket ----------
__global__ __launch_bounds__(256) void bin_stage(const int* __restrict__ ei,
                                                 int* __restrict__ bucket_next,
                                                 int2* __restrict__ staged, int nedges) {
    __shared__ int cnt[NBUK];
    __shared__ int ofs[NBUK];
    __shared__ int run[NBUK];
    __shared__ int gbase[NBUK];
    __shared__ int ssum[256];
    __shared__ int2 sedge[CHUNK];
    const int tid = threadIdx.x;
    const int base = blockIdx.x * CHUNK;
    const int nloc = min(CHUNK, nedges - base);

    for (int i = tid; i < NBUK; i += 256) { cnt[i] = 0; run[i] = 0; }
    __syncthreads();

    int r[16], c[16];
#pragma unroll
    for (int k = 0; k < 16; ++k) {
        int loc = tid + k * 256;
        bool ok = loc < nloc;
        int idx = base + loc;
        r[k] = ok ? ei[idx] : -1;
        c[k] = ok ? ei[nedges + idx] : 0;
        if (ok) atomicAdd(&cnt[r[k] >> 8], 1);
    }
    __syncthreads();

    int a0 = (2 * tid < NBUK) ? cnt[2 * tid] : 0;
    int a1 = (2 * tid + 1 < NBUK) ? cnt[2 * tid + 1] : 0;
    ssum[tid] = a0 + a1;
    __syncthreads();
    for (int off = 1; off < 256; off <<= 1) {
        int v = ssum[tid];
        int add = (tid >= off) ? ssum[tid - off] : 0;
        __syncthreads();
        ssum[tid] = v + add;
        __syncthreads();
    }
    int excl = (tid > 0) ? ssum[tid - 1] : 0;
    if (2 * tid < NBUK) ofs[2 * tid] = excl;
    if (2 * tid + 1 < NBUK) ofs[2 * tid + 1] = excl + a0;
    __syncthreads();

#pragma unroll
    for (int k = 0; k < 16; ++k) {
        if (r[k] >= 0) {
            int b = r[k] >> 8;
            int p = atomicAdd(&run[b], 1);
            sedge[ofs[b] + p] = make_int2(r[k], c[k]);
        }
    }
    __syncthreads();

    for (int b = tid; b < NBUK; b += 256) {
        int n = cnt[b];
        gbase[b] = n ? atomicAdd(&bucket_next[b], n) : 0;
    }
    __syncthreads();

    for (int i = tid; i < nloc; i += 256) {
        int2 e = sedge[i];
        int b = e.x >> 8;
        staged[gbase[b] + (i - ofs[b])] = e;
    }
}

// ---------- phase C1: per-bucket degree count -> rowptr slice + deg_inv_sqrt ----------
__global__ __launch_bounds__(256) void bin_count(const int2* __restrict__ staged,
                                                 const int* __restrict__ bucket_base,
                                                 int* __restrict__ rowptr, float* __restrict__ dis,
                                                 int nnodes, int nedges) {
    __shared__ int deg[256];
    __shared__ int ssum[256];
    const int b = blockIdx.x;
    const int n0 = b << 8;
    const int nend = min(n0 + 256, nnodes);
    const int nloc = nend - n0;
    const int tid = threadIdx.x;
    deg[tid] = 0;
    __syncthreads();
    const int ebase = bucket_base[b];
    const int ecount = bucket_base[b + 1] - ebase;
    for (int i = tid; i < ecount; i += 256) {
        atomicAdd(&deg[staged[ebase + i].x - n0], 1);
    }
    __syncthreads();
    int d = deg[tid];
    if (tid < nloc) {
        float df = (float)d;
        dis[n0 + tid] = (d > 0) ? (1.0f / sqrtf(fmaxf(df, 1.f))) : 0.f;
    }
    ssum[tid] = d;
    __syncthreads();
    for (int off = 1; off < 256; off <<= 1) {
        int v = ssum[tid];
        int add = (tid >= off) ? ssum[tid - off] : 0;
        __syncthreads();
        ssum[tid] = v + add;
        __syncthreads();
    }
    int excl = (tid > 0) ? ssum[tid - 1] : 0;
    if (tid < nloc) rowptr[n0 + tid] = ebase + excl;
    if (b == NBUK - 1 && tid == 0) rowptr[nnodes] = nedges;
}

// ---------- phase C2: per-bucket exact CSR placement + norm weight ----------
__global__ __launch_bounds__(256) void bin_place(const int2* __restrict__ staged,
                                                 const int* __restrict__ rowptr,
                                                 const float* __restrict__ dis,
                                                 int2* __restrict__ colw, int nnodes) {
    __shared__ int rp[256];
    __shared__ int nx[256];
    __shared__ float dl[256];
    const int b = blockIdx.x;
    const int n0 = b << 8;
    const int nend = min(n0 + 256, nnodes);
    const int nloc = nend - n0;
    const int tid = threadIdx.x;
    if (tid < nloc) {
        rp[tid] = rowptr[n0 + tid];
        dl[tid] = dis[n0 + tid];
    }
    nx[tid] = 0;
    __syncthreads();
    const int ebase = rowptr[n0];
    const int ecount = rowptr[nend] - ebase;
    for (int i = tid; i < ecount; i += 256) {
        int2 e = staged[ebase + i];
        int rrel = e.x - n0;
        int p = atomicAdd(&nx[rrel], 1);
        float w = -dl[rrel] * dis[e.y];
        colw[rp[rrel] + p] = make_int2(e.y, __float_as_int(w));
    }
}

// ---------- merged weight packing into MFMA B-fragment layouts (fp16) ----------
__global__ void fold_wf(const float* __restrict__ W1, const float* __restrict__ W2,
                        __half* __restrict__ W1f, __half* __restrict__ W2f) {
    int i = blockIdx.x * blockDim.x + threadIdx.x;
    if (i < 12288) {                       // layer-1: [4 ct][6 kh][64 lane][8 j]
        int j = i & 7;
        int lane = (i >> 3) & 63;
        int rest = i >> 9;
        int kh = rest % 6;
        int ct = rest / 6;
        int term = kh >> 1;
        int k = ((kh & 1) << 5) | ((lane >> 4) << 3) | j;
        int c = (ct << 4) | (lane & 15);
        float w0 = W1[k * 64 + c];
        float w1 = W1[4096 + k * 64 + c];
        float w2 = W1[2 * 4096 + k * 64 + c];
        float v = (term == 0) ? (w0 - w2) : ((term == 1) ? w1 : 2.0f * w2);
        W1f[i] = __float2half(v);
    } else if (i < 12288 + 6144) {         // layer-2: [6 ct][2 kh][64 lane][8 j]
        int ii = i - 12288;
        int j = ii & 7;
        int lane = (ii >> 3) & 63;
        int rest = ii >> 9;
        int kh = rest & 1;
        int ct = rest >> 1;
        int k = (kh << 5) | ((lane >> 4) << 3) | j;
        int cg = ct * 16 + (lane & 15);
        int seg = cg >> 5;
        int c = cg & 31;
        float w0 = W2[k * 32 + c];
        float w1 = W2[2048 + k * 32 + c];
        float w2 = W2[2 * 2048 + k * 32 + c];
        float v = (seg == 0) ? (w0 - w2) : ((seg == 1) ? w1 : 2.0f * w2);
        W2f[ii] = __float2half(v);
    }
}

// ---------- prop64: 16 lanes/edge (4 ch, 8B loads), 4 edges/instr ----------
__global__ __launch_bounds__(256) void prop_gather_h(const __half* __restrict__ t,
                                                     const int* __restrict__ rowptr,
                                                     const int2* __restrict__ colw,
                                                     __half* __restrict__ out, int nnodes) {
    int node = blockIdx.x * 4 + (threadIdx.x >> 6);
    if (node >= nnodes) return;
    int lane = threadIdx.x & 63;
    int g = lane >> 4;     // edge group 0..3
    int cq = lane & 15;    // channel quad: ch 4*cq .. 4*cq+3
    int s = rowptr[node];
    int e = rowptr[node + 1];
    float acc[4] = {0.f, 0.f, 0.f, 0.f};
    for (int base = s; base < e; base += 64) {
        int m = e - base;
        if (m > 64) m = 64;
        int2 cw = (lane < m) ? colw[base + lane] : make_int2(0, 0);
        int iters = (m + 3) >> 2;
        int it = 0;
        for (; it + 1 < iters; it += 2) {
            int j0 = (it << 2) | g;
            int j1 = j0 + 4;
            int c0 = __shfl(cw.x, j0);
            float w0 = __int_as_float(__shfl(cw.y, j0));
            int c1 = __shfl(cw.x, j1);
            float w1 = __int_as_float(__shfl(cw.y, j1));
            float2 raw0 = ((const float2*)(t + (size_t)c0 * 64))[cq];
            float2 raw1 = ((const float2*)(t + (size_t)c1 * 64))[cq];
            const __half2* h0 = (const __half2*)&raw0;
            const __half2* h1 = (const __half2*)&raw1;
            float2 f00 = __half22float2(h0[0]);
            float2 f01 = __half22float2(h0[1]);
            float2 f10 = __half22float2(h1[0]);
            float2 f11 = __half22float2(h1[1]);
            acc[0] += w0 * f00.x + w1 * f10.x;
            acc[1] += w0 * f00.y + w1 * f10.y;
            acc[2] += w0 * f01.x + w1 * f11.x;
            acc[3] += w0 * f01.y + w1 * f11.y;
        }
        if (it < iters) {
            int j0 = (it << 2) | g;
            int c0 = __shfl(cw.x, j0);
            float w0 = __int_as_float(__shfl(cw.y, j0));
            float2 raw0 = ((const float2*)(t + (size_t)c0 * 64))[cq];
            const __half2* h0 = (const __half2*)&raw0;
            float2 f00 = __half22float2(h0[0]);
            float2 f01 = __half22float2(h0[1]);
            acc[0] += w0 * f00.x;
            acc[1] += w0 * f00.y;
            acc[2] += w0 * f01.x;
            acc[3] += w0 * f01.y;
        }
    }
#pragma unroll
    for (int i = 0; i < 4; ++i) {
        acc[i] += __shfl_xor(acc[i], 16);
        acc[i] += __shfl_xor(acc[i], 32);
    }
    if (g == 0) {
        __half2 tmp[2];
        tmp[0] = __floats2half2_rn(acc[0], acc[1]);
        tmp[1] = __floats2half2_rn(acc[2], acc[3]);
        ((float2*)(out + (size_t)node * 64))[cq] = *(float2*)tmp;
    }
}

// ---------- prop32: 16 lanes/edge (2 ch, 4B loads), 4 edges/instr ----------
template <bool F32OUT>
__global__ __launch_bounds__(256) void prop_gather32(const __half* __restrict__ t,
                                                     const int* __restrict__ rowptr,
                                                     const int2* __restrict__ colw,
                                                     const void* __restrict__ addin,
                                                     void* __restrict__ outv, int nnodes) {
    int node = blockIdx.x * 4 + (threadIdx.x >> 6);
    if (node >= nnodes) return;
    int lane = threadIdx.x & 63;
    int g = lane >> 4;     // edge group 0..3
    int cq = lane & 15;    // channel pair: ch 2*cq, 2*cq+1
    int s = rowptr[node];
    int e = rowptr[node + 1];
    float acc0 = 0.f, acc1 = 0.f;
    for (int base = s; base < e; base += 64) {
        int m = e - base;
        if (m > 64) m = 64;
        int2 cw = (lane < m) ? colw[base + lane] : make_int2(0, 0);
        int iters = (m + 3) >> 2;
        int it = 0;
        for (; it + 1 < iters; it += 2) {
            int j0 = (it << 2) | g;
            int j1 = j0 + 4;
            int c0 = __shfl(cw.x, j0);
            float w0 = __int_as_float(__shfl(cw.y, j0));
            int c1 = __shfl(cw.x, j1);
            float w1 = __int_as_float(__shfl(cw.y, j1));
            __half2 r0 = ((const __half2*)(t + (size_t)c0 * 32))[cq];
            __half2 r1 = ((const __half2*)(t + (size_t)c1 * 32))[cq];
            float2 f0 = __half22float2(r0);
            float2 f1 = __half22float2(r1);
            acc0 += w0 * f0.x + w1 * f1.x;
            acc1 += w0 * f0.y + w1 * f1.y;
        }
        if (it < iters) {
            int j0 = (it << 2) | g;
            int c0 = __shfl(cw.x, j0);
            float w0 = __int_as_float(__shfl(cw.y, j0));
            __half2 r0 = ((const __half2*)(t + (size_t)c0 * 32))[cq];
            float2 f0 = __half22float2(r0);
            acc0 += w0 * f0.x;
            acc1 += w0 * f0.y;
        }
    }
    acc0 += __shfl_xor(acc0, 16); acc1 += __shfl_xor(acc1, 16);
    acc0 += __shfl_xor(acc0, 32); acc1 += __shfl_xor(acc1, 32);
    if (g == 0) {
        if (F32OUT) {
            const float* add = (const float*)addin;
            float* out = (float*)outv;
            float2 a = ((const float2*)(add + (size_t)node * 32))[cq];
            a.x += acc0;
            a.y += acc1;
            ((float2*)(out + (size_t)node * 32))[cq] = a;
        } else {
            const __half* add = (const __half*)addin;
            __half* out = (__half*)outv;
            float2 af = __half22float2(((const __half2*)(add + (size_t)node * 32))[cq]);
            ((__half2*)(out + (size_t)node * 32))[cq] = __floats2half2_rn(acc0 + af.x, acc1 + af.y);
        }
    }
}

// ---------- FUSED both-layer MFMA GEMM ----------
// Layer 1 computes the 16x64 H-tile (relu'd) in C-layout, round-trips it through a
// per-wave LDS tile (stride 72 halves: 16B-aligned b128 reads, banks 4*(m+quad)%32)
// into A-fragment layout, then runs layer 2. Hh global buffer eliminated.
__global__ __launch_bounds__(256) void gemm_fused(const __half* __restrict__ A0,
                                                  const __half* __restrict__ A1,
                                                  const __half* __restrict__ A2,
                                                  const __half* __restrict__ W1f,
                                                  const float* __restrict__ b1,
                                                  const __half* __restrict__ W2f,
                                                  const float* __restrict__ b2,
                                                  float* __restrict__ P0,
                                                  __half* __restrict__ G1,
                                                  __half* __restrict__ G2, int nnodes) {
    __shared__ __align__(16) __half htile[4][16 * 72];   // 9 KB
    const int wave = threadIdx.x >> 6;
    const int lane = threadIdx.x & 63;
    const int node0 = blockIdx.x * 64 + wave * 16;
    const int m = lane & 15;
    const int quad = lane >> 4;
    int arow = node0 + m;
    if (arow >= nnodes) arow = nnodes - 1;   // clamp: garbage rows never stored globally

    // ---- layer 1 ----
    const __half* Ap[3] = {A0, A1, A2};
    f16x8 a[6];
#pragma unroll
    for (int kh = 0; kh < 6; ++kh) {
        const __half* A = Ap[kh >> 1];
        a[kh] = *(const f16x8*)(A + (size_t)arow * 64 + ((kh & 1) << 5) + (quad << 3));
    }
    __half* ht = htile[wave];
#pragma unroll
    for (int ct = 0; ct < 4; ++ct) {
        f32x4 acc = {0.f, 0.f, 0.f, 0.f};
#pragma unroll
        for (int kh = 0; kh < 6; ++kh) {
            f16x8 b = *(const f16x8*)(W1f + ((size_t)(ct * 6 + kh) * 64 + lane) * 8);
            acc = __builtin_amdgcn_mfma_f32_16x16x32_f16(a[kh], b, acc, 0, 0, 0);
        }
        int col = (ct << 4) | m;
        float bias = b1[col];
#pragma unroll
        for (int r = 0; r < 4; ++r) {
            ht[(quad * 4 + r) * 72 + col] = __float2half(fmaxf(acc[r] + bias, 0.f));
        }
    }
    __syncthreads();

    // ---- layer 2: A-frags straight from the LDS tile ----
    f16x8 h0 = *(const f16x8*)(ht + m * 72 + (quad << 3));
    f16x8 h1 = *(const f16x8*)(ht + m * 72 + 32 + (quad << 3));
#pragma unroll
    for (int ct = 0; ct < 6; ++ct) {
        f32x4 acc = {0.f, 0.f, 0.f, 0.f};
        f16x8 b0 = *(const f16x8*)(W2f + ((size_t)(ct * 2 + 0) * 64 + lane) * 8);
        f16x8 b1v = *(const f16x8*)(W2f + ((size_t)(ct * 2 + 1) * 64 + lane) * 8);
        acc = __builtin_amdgcn_mfma_f32_16x16x32_f16(h0, b0, acc, 0, 0, 0);
        acc = __builtin_amdgcn_mfma_f32_16x16x32_f16(h1, b1v, acc, 0, 0, 0);
        int seg = ct >> 1;                      // wave-uniform
        int c = ((ct & 1) << 4) | m;            // col within segment
#pragma unroll
        for (int r = 0; r < 4; ++r) {
            int n = node0 + (quad << 2) + r;
            if (n >= nnodes) continue;
            float v = acc[r];
            if (seg == 0)      P0[(size_t)n * 32 + c] = v + b2[c];
            else if (seg == 1) G1[(size_t)n * 32 + c] = __float2half(v);
            else               G2[(size_t)n * 32 + c] = __float2half(v);
        }
    }
}

extern "C" void kernel_launch(void* const* d_in, const int* in_sizes, int n_in,
                              void* d_out, int out_size, void* d_ws, size_t ws_size,
                              hipStream_t stream) {
    const float* x  = (const float*)d_in[0];
    const int*   ei = (const int*)d_in[1];
    const float* W1 = (const float*)d_in[2];
    const float* b1 = (const float*)d_in[3];
    const float* W2 = (const float*)d_in[4];
    const float* b2 = (const float*)d_in[5];
    float* out = (float*)d_out;

    const int NN = N_NODES_C;
    const int NE = N_EDGES_C;
    const size_t HFEAT_BYTES = (size_t)NN * 64 * sizeof(__half);
    const size_t H32_BYTES = (size_t)NN * 32 * sizeof(__half);

    char* ws = (char*)d_ws;
    size_t off = 0;
    auto alloc = [&](size_t bytes) -> void* {
        void* p = ws + off;
        off += (bytes + 255) & ~(size_t)255;
        return p;
    };
    int*    bucket_cnt  = (int*)alloc((size_t)NBUK * 4);
    int*    bucket_base = (int*)alloc((size_t)(NBUK + 1) * 4);
    int*    bucket_next = (int*)alloc((size_t)NBUK * 4);
    int*    rowptr      = (int*)alloc((size_t)(NN + 1) * 4);
    float*  dis         = (float*)alloc((size_t)NN * 4);
    int2*   staged      = (int2*)alloc((size_t)NE * 8);
    int2*   colw        = (int2*)alloc((size_t)NE * 8);
    __half* xh          = (__half*)alloc(HFEAT_BYTES);
    __half* T1h         = (__half*)alloc(HFEAT_BYTES);   // layer1: T1; layer2: G1
    __half* T2h         = (__half*)alloc(HFEAT_BYTES);   // layer1: T2; layer2: G2
    __half* Qh          = (__half*)alloc(H32_BYTES);
    float*  P0          = (float*)alloc((size_t)NN * 32 * 4);
    __half* W1f         = (__half*)alloc((size_t)4 * 6 * 64 * 8 * 2);   // 24 KB
    __half* W2f         = (__half*)alloc((size_t)6 * 2 * 64 * 8 * 2);   // 12 KB

    const int PROPB = (NN + 3) / 4;
    const int CONV4 = NN * 64 / 4;
    const int CONVB = (CONV4 + 255) / 256;
    const int BINB = (NE + CHUNK - 1) / CHUNK;
    const int GEMMB = (NN + 63) / 64;

    // ---- CSR build (bucket-atomic) + weight packing + x->fp16 ----
    hipMemsetAsync(bucket_cnt, 0, (size_t)NBUK * 4, stream);
    hist_f2h<<<BINB + CONVB, 256, 0, stream>>>(ei, bucket_cnt, x, xh, NE, CONV4, BINB);
    bucket_scan<<<1, 256, 0, stream>>>(bucket_cnt, bucket_base, bucket_next, NBUK);
    bin_stage<<<BINB, 256, 0, stream>>>(ei, bucket_next, staged, NE);
    bin_count<<<NBUK, 256, 0, stream>>>(staged, bucket_base, rowptr, dis, NN, NE);
    bin_place<<<NBUK, 256, 0, stream>>>(staged, rowptr, dis, colw, NN);
    fold_wf<<<(18432 + 255) / 256, 256, 0, stream>>>(W1, W2, W1f, W2f);

    // ---- layer 1 props, then fused both-layer GEMM ----
    prop_gather_h<<<PROPB, 256, 0, stream>>>(xh, rowptr, colw, T1h, NN);
    prop_gather_h<<<PROPB, 256, 0, stream>>>(T1h, rowptr, colw, T2h, NN);
    gemm_fused<<<GEMMB, 256, 0, stream>>>(xh, T1h, T2h, W1f, b1, W2f, b2, P0, T1h, T2h, NN);

    // ---- layer 2 (factored): out = P0 + prop(G1 + prop(G2)) ----
    prop_gather32<false><<<PROPB, 256, 0, stream>>>(T2h, rowptr, colw, T1h, Qh, NN);
    prop_gather32<true><<<PROPB, 256, 0, stream>>>(Qh, rowptr, colw, P0, out, NN);
}

// Round 17
// 256.070 us; speedup vs baseline: 6.6492x; 1.1140x over previous
//
#include <hip/hip_runtime.h>
#include <hip/hip_fp16.h>

#define N_NODES_C 100000
#define N_EDGES_C 1200000
#define NBUK ((N_NODES_C + 255) >> 8)   // 391 buckets of 256 nodes
#define CHUNK 4096                       // edges per binning block

typedef _Float16 f16x8 __attribute__((ext_vector_type(8)));
typedef float f32x4 __attribute__((ext_vector_type(4)));

// ---------- merged: bucket histogram (blocks 0..histB-1) + fp32->fp16 convert ----------
__global__ __launch_bounds__(256) void hist_f2h(const int* __restrict__ ei,
                                                int* __restrict__ bucket_cnt,
                                                const float* __restrict__ x,
                                                __half* __restrict__ xh,
                                                int nedges, int n4, int histB) {
    __shared__ int cnt[NBUK];
    const int tid = threadIdx.x;
    if (blockIdx.x < histB) {
        const int base = blockIdx.x * CHUNK;
        const int nloc = min(CHUNK, nedges - base);
        for (int i = tid; i < NBUK; i += 256) cnt[i] = 0;
        __syncthreads();
        for (int i = tid; i < nloc; i += 256) atomicAdd(&cnt[ei[base + i] >> 8], 1);
        __syncthreads();
        for (int b = tid; b < NBUK; b += 256) {
            int n = cnt[b];
            if (n) atomicAdd(&bucket_cnt[b], n);
        }
    } else {
        int i = (blockIdx.x - histB) * 256 + tid;
        if (i < n4) {
            float4 v = ((const float4*)x)[i];
            __half2 tmp[2];
            tmp[0] = __floats2half2_rn(v.x, v.y);
            tmp[1] = __floats2half2_rn(v.z, v.w);
            ((float2*)xh)[i] = *(float2*)tmp;
        }
    }
}

// ---------- parallel scan of 391 bucket counts -> bucket_base / bucket_next ----------
__global__ __launch_bounds__(256) void bucket_scan(const int* __restrict__ bucket_cnt,
                                                   int* __restrict__ bucket_base,
                                                   int* __restrict__ bucket_next, int nb) {
    __shared__ int s[256];
    const int tid = threadIdx.x;
    int a0 = (2 * tid < nb) ? bucket_cnt[2 * tid] : 0;
    int a1 = (2 * tid + 1 < nb) ? bucket_cnt[2 * tid + 1] : 0;
    s[tid] = a0 + a1;
    __syncthreads();
    for (int off = 1; off < 256; off <<= 1) {
        int v = s[tid];
        int add = (tid >= off) ? s[tid - off] : 0;
        __syncthreads();
        s[tid] = v + add;
        __syncthreads();
    }
    int excl = (tid > 0) ? s[tid - 1] : 0;
    if (2 * tid < nb) { bucket_base[2 * tid] = excl; bucket_next[2 * tid] = excl; }
    if (2 * tid + 1 < nb) { bucket_base[2 * tid + 1] = excl + a0; bucket_next[2 * tid + 1] = excl + a0; }
    if (tid == 255) bucket_base[nb] = s[255];
}

// ---------- phase B: LDS-binned staging of (r,c) grouped by 256-node bucket ----------
__global__ __launch_bounds__(256) void bin_stage(const int* __restrict__ ei,
                                                 int* __restrict__ bucket_next,
                                                 int2* __restrict__ staged, int nedges) {
    __shared__ int cnt[NBUK];
    __shared__ int ofs[NBUK];
    __shared__ int run[NBUK];
    __shared__ int gbase[NBUK];
    __shared__ int ssum[256];
    __shared__ int2 sedge[CHUNK];
    const int tid = threadIdx.x;
    const int base = blockIdx.x * CHUNK;
    const int nloc = min(CHUNK, nedges - base);

    for (int i = tid; i < NBUK; i += 256) { cnt[i] = 0; run[i] = 0; }
    __syncthreads();

    int r[16], c[16];
#pragma unroll
    for (int k = 0; k < 16; ++k) {
        int loc = tid + k * 256;
        bool ok = loc < nloc;
        int idx = base + loc;
        r[k] = ok ? ei[idx] : -1;
        c[k] = ok ? ei[nedges + idx] : 0;
        if (ok) atomicAdd(&cnt[r[k] >> 8], 1);
    }
    __syncthreads();

    int a0 = (2 * tid < NBUK) ? cnt[2 * tid] : 0;
    int a1 = (2 * tid + 1 < NBUK) ? cnt[2 * tid + 1] : 0;
    ssum[tid] = a0 + a1;
    __syncthreads();
    for (int off = 1; off < 256; off <<= 1) {
        int v = ssum[tid];
        int add = (tid >= off) ? ssum[tid - off] : 0;
        __syncthreads();
        ssum[tid] = v + add;
        __syncthreads();
    }
    int excl = (tid > 0) ? ssum[tid - 1] : 0;
    if (2 * tid < NBUK) ofs[2 * tid] = excl;
    if (2 * tid + 1 < NBUK) ofs[2 * tid + 1] = excl + a0;
    __syncthreads();

#pragma unroll
    for (int k = 0; k < 16; ++k) {
        if (r[k] >= 0) {
            int b = r[k] >> 8;
            int p = atomicAdd(&run[b], 1);
            sedge[ofs[b] + p] = make_int2(r[k], c[k]);
        }
    }
    __syncthreads();

    for (int b = tid; b < NBUK; b += 256) {
        int n = cnt[b];
        gbase[b] = n ? atomicAdd(&bucket_next[b], n) : 0;
    }
    __syncthreads();

    for (int i = tid; i < nloc; i += 256) {
        int2 e = sedge[i];
        int b = e.x >> 8;
        staged[gbase[b] + (i - ofs[b])] = e;
    }
}

// ---------- phase C1: per-bucket degree count -> rowptr slice + deg_inv_sqrt ----------
__global__ __launch_bounds__(256) void bin_count(const int2* __restrict__ staged,
                                                 const int* __restrict__ bucket_base,
                                                 int* __restrict__ rowptr, float* __restrict__ dis,
                                                 int nnodes, int nedges) {
    __shared__ int deg[256];
    __shared__ int ssum[256];
    const int b = blockIdx.x;
    const int n0 = b << 8;
    const int nend = min(n0 + 256, nnodes);
    const int nloc = nend - n0;
    const int tid = threadIdx.x;
    deg[tid] = 0;
    __syncthreads();
    const int ebase = bucket_base[b];
    const int ecount = bucket_base[b + 1] - ebase;
    for (int i = tid; i < ecount; i += 256) {
        atomicAdd(&deg[staged[ebase + i].x - n0], 1);
    }
    __syncthreads();
    int d = deg[tid];
    if (tid < nloc) {
        float df = (float)d;
        dis[n0 + tid] = (d > 0) ? (1.0f / sqrtf(fmaxf(df, 1.f))) : 0.f;
    }
    ssum[tid] = d;
    __syncthreads();
    for (int off = 1; off < 256; off <<= 1) {
        int v = ssum[tid];
        int add = (tid >= off) ? ssum[tid - off] : 0;
        __syncthreads();
        ssum[tid] = v + add;
        __syncthreads();
    }
    int excl = (tid > 0) ? ssum[tid - 1] : 0;
    if (tid < nloc) rowptr[n0 + tid] = ebase + excl;
    if (b == NBUK - 1 && tid == 0) rowptr[nnodes] = nedges;
}

// ---------- phase C2: per-bucket exact CSR placement + norm weight ----------
__global__ __launch_bounds__(256) void bin_place(const int2* __restrict__ staged,
                                                 const int* __restrict__ rowptr,
                                                 const float* __restrict__ dis,
                                                 int2* __restrict__ colw, int nnodes) {
    __shared__ int rp[256];
    __shared__ int nx[256];
    __shared__ float dl[256];
    const int b = blockIdx.x;
    const int n0 = b << 8;
    const int nend = min(n0 + 256, nnodes);
    const int nloc = nend - n0;
    const int tid = threadIdx.x;
    if (tid < nloc) {
        rp[tid] = rowptr[n0 + tid];
        dl[tid] = dis[n0 + tid];
    }
    nx[tid] = 0;
    __syncthreads();
    const int ebase = rowptr[n0];
    const int ecount = rowptr[nend] - ebase;
    for (int i = tid; i < ecount; i += 256) {
        int2 e = staged[ebase + i];
        int rrel = e.x - n0;
        int p = atomicAdd(&nx[rrel], 1);
        float w = -dl[rrel] * dis[e.y];
        colw[rp[rrel] + p] = make_int2(e.y, __float_as_int(w));
    }
}

// ---------- merged weight packing into MFMA B-fragment layouts (fp16) ----------
__global__ void fold_wf(const float* __restrict__ W1, const float* __restrict__ W2,
                        __half* __restrict__ W1f, __half* __restrict__ W2f) {
    int i = blockIdx.x * blockDim.x + threadIdx.x;
    if (i < 12288) {                       // layer-1: [4 ct][6 kh][64 lane][8 j]
        int j = i & 7;
        int lane = (i >> 3) & 63;
        int rest = i >> 9;
        int kh = rest % 6;
        int ct = rest / 6;
        int term = kh >> 1;
        int k = ((kh & 1) << 5) | ((lane >> 4) << 3) | j;
        int c = (ct << 4) | (lane & 15);
        float w0 = W1[k * 64 + c];
        float w1 = W1[4096 + k * 64 + c];
        float w2 = W1[2 * 4096 + k * 64 + c];
        float v = (term == 0) ? (w0 - w2) : ((term == 1) ? w1 : 2.0f * w2);
        W1f[i] = __float2half(v);
    } else if (i < 12288 + 6144) {         // layer-2: [6 ct][2 kh][64 lane][8 j]
        int ii = i - 12288;
        int j = ii & 7;
        int lane = (ii >> 3) & 63;
        int rest = ii >> 9;
        int kh = rest & 1;
        int ct = rest >> 1;
        int k = (kh << 5) | ((lane >> 4) << 3) | j;
        int cg = ct * 16 + (lane & 15);
        int seg = cg >> 5;
        int c = cg & 31;
        float w0 = W2[k * 32 + c];
        float w1 = W2[2048 + k * 32 + c];
        float w2 = W2[2 * 2048 + k * 32 + c];
        float v = (seg == 0) ? (w0 - w2) : ((seg == 1) ? w1 : 2.0f * w2);
        W2f[ii] = __float2half(v);
    }
}

// ---------- prop64: 8-lane groups, 8 independent nodes/wave, serial edge walk ----------
// Lane = 16B (8 ch) of the 128B row; colw reads are group-broadcast (L1-hot);
// no shuffles, no reduce. Unroll x2 -> up to 16 gathers in flight per wave.
__global__ __launch_bounds__(256) void prop_gather_h(const __half* __restrict__ t,
                                                     const int* __restrict__ rowptr,
                                                     const int2* __restrict__ colw,
                                                     __half* __restrict__ out, int nnodes) {
    int grp = threadIdx.x >> 3;          // 0..31 within block
    int ln = threadIdx.x & 7;            // 16B chunk: ch 8*ln .. 8*ln+7
    int node = blockIdx.x * 32 + grp;
    if (node >= nnodes) return;
    int s = rowptr[node];
    int e = rowptr[node + 1];
    float acc[8] = {0.f, 0.f, 0.f, 0.f, 0.f, 0.f, 0.f, 0.f};
    int i = s;
    for (; i + 1 < e; i += 2) {
        int2 cw0 = colw[i];
        int2 cw1 = colw[i + 1];
        float w0 = __int_as_float(cw0.y);
        float w1 = __int_as_float(cw1.y);
        float4 r0 = ((const float4*)(t + (size_t)cw0.x * 64))[ln];
        float4 r1 = ((const float4*)(t + (size_t)cw1.x * 64))[ln];
        const __half2* h0 = (const __half2*)&r0;
        const __half2* h1 = (const __half2*)&r1;
#pragma unroll
        for (int q = 0; q < 4; ++q) {
            float2 f0 = __half22float2(h0[q]);
            float2 f1 = __half22float2(h1[q]);
            acc[2 * q + 0] += w0 * f0.x + w1 * f1.x;
            acc[2 * q + 1] += w0 * f0.y + w1 * f1.y;
        }
    }
    if (i < e) {
        int2 cw0 = colw[i];
        float w0 = __int_as_float(cw0.y);
        float4 r0 = ((const float4*)(t + (size_t)cw0.x * 64))[ln];
        const __half2* h0 = (const __half2*)&r0;
#pragma unroll
        for (int q = 0; q < 4; ++q) {
            float2 f0 = __half22float2(h0[q]);
            acc[2 * q + 0] += w0 * f0.x;
            acc[2 * q + 1] += w0 * f0.y;
        }
    }
    __half2 tmp[4];
    tmp[0] = __floats2half2_rn(acc[0], acc[1]);
    tmp[1] = __floats2half2_rn(acc[2], acc[3]);
    tmp[2] = __floats2half2_rn(acc[4], acc[5]);
    tmp[3] = __floats2half2_rn(acc[6], acc[7]);
    ((float4*)(out + (size_t)node * 64))[ln] = *(float4*)tmp;
}

// ---------- prop32: 8-lane groups, 8 nodes/wave; lane = 8B (4 ch) of the 64B row ----------
// Fused add-input; fp16 (Q) or fp32 (final out) epilogue. No shuffles, no reduce.
template <bool F32OUT>
__global__ __launch_bounds__(256) void prop_gather32(const __half* __restrict__ t,
                                                     const int* __restrict__ rowptr,
                                                     const int2* __restrict__ colw,
                                                     const void* __restrict__ addin,
                                                     void* __restrict__ outv, int nnodes) {
    int grp = threadIdx.x >> 3;          // 0..31 within block
    int ln = threadIdx.x & 7;            // 8B chunk: ch 4*ln .. 4*ln+3
    int node = blockIdx.x * 32 + grp;
    if (node >= nnodes) return;
    int s = rowptr[node];
    int e = rowptr[node + 1];
    float acc[4] = {0.f, 0.f, 0.f, 0.f};
    int i = s;
    for (; i + 1 < e; i += 2) {
        int2 cw0 = colw[i];
        int2 cw1 = colw[i + 1];
        float w0 = __int_as_float(cw0.y);
        float w1 = __int_as_float(cw1.y);
        float2 r0 = ((const float2*)(t + (size_t)cw0.x * 32))[ln];
        float2 r1 = ((const float2*)(t + (size_t)cw1.x * 32))[ln];
        const __half2* h0 = (const __half2*)&r0;
        const __half2* h1 = (const __half2*)&r1;
#pragma unroll
        for (int q = 0; q < 2; ++q) {
            float2 f0 = __half22float2(h0[q]);
            float2 f1 = __half22float2(h1[q]);
            acc[2 * q + 0] += w0 * f0.x + w1 * f1.x;
            acc[2 * q + 1] += w0 * f0.y + w1 * f1.y;
        }
    }
    if (i < e) {
        int2 cw0 = colw[i];
        float w0 = __int_as_float(cw0.y);
        float2 r0 = ((const float2*)(t + (size_t)cw0.x * 32))[ln];
        const __half2* h0 = (const __half2*)&r0;
#pragma unroll
        for (int q = 0; q < 2; ++q) {
            float2 f0 = __half22float2(h0[q]);
            acc[2 * q + 0] += w0 * f0.x;
            acc[2 * q + 1] += w0 * f0.y;
        }
    }
    if (F32OUT) {
        const float* add = (const float*)addin;
        float* out = (float*)outv;
        float4 a = ((const float4*)(add + (size_t)node * 32))[ln];
        a.x += acc[0]; a.y += acc[1]; a.z += acc[2]; a.w += acc[3];
        ((float4*)(out + (size_t)node * 32))[ln] = a;
    } else {
        const __half* add = (const __half*)addin;
        __half* out = (__half*)outv;
        float2 raw = ((const float2*)(add + (size_t)node * 32))[ln];
        const __half2* hp = (const __half2*)&raw;
        float2 a0 = __half22float2(hp[0]);
        float2 a1 = __half22float2(hp[1]);
        __half2 tmp[2];
        tmp[0] = __floats2half2_rn(acc[0] + a0.x, acc[1] + a0.y);
        tmp[1] = __floats2half2_rn(acc[2] + a1.x, acc[3] + a1.y);
        ((float2*)(out + (size_t)node * 32))[ln] = *(float2*)tmp;
    }
}

// ---------- FUSED both-layer MFMA GEMM ----------
__global__ __launch_bounds__(256) void gemm_fused(const __half* __restrict__ A0,
                                                  const __half* __restrict__ A1,
                                                  const __half* __restrict__ A2,
                                                  const __half* __restrict__ W1f,
                                                  const float* __restrict__ b1,
                                                  const __half* __restrict__ W2f,
                                                  const float* __restrict__ b2,
                                                  float* __restrict__ P0,
                                                  __half* __restrict__ G1,
                                                  __half* __restrict__ G2, int nnodes) {
    __shared__ __align__(16) __half htile[4][16 * 72];   // 9 KB
    const int wave = threadIdx.x >> 6;
    const int lane = threadIdx.x & 63;
    const int node0 = blockIdx.x * 64 + wave * 16;
    const int m = lane & 15;
    const int quad = lane >> 4;
    int arow = node0 + m;
    if (arow >= nnodes) arow = nnodes - 1;   // clamp: garbage rows never stored globally

    // ---- layer 1 ----
    const __half* Ap[3] = {A0, A1, A2};
    f16x8 a[6];
#pragma unroll
    for (int kh = 0; kh < 6; ++kh) {
        const __half* A = Ap[kh >> 1];
        a[kh] = *(const f16x8*)(A + (size_t)arow * 64 + ((kh & 1) << 5) + (quad << 3));
    }
    __half* ht = htile[wave];
#pragma unroll
    for (int ct = 0; ct < 4; ++ct) {
        f32x4 acc = {0.f, 0.f, 0.f, 0.f};
#pragma unroll
        for (int kh = 0; kh < 6; ++kh) {
            f16x8 b = *(const f16x8*)(W1f + ((size_t)(ct * 6 + kh) * 64 + lane) * 8);
            acc = __builtin_amdgcn_mfma_f32_16x16x32_f16(a[kh], b, acc, 0, 0, 0);
        }
        int col = (ct << 4) | m;
        float bias = b1[col];
#pragma unroll
        for (int r = 0; r < 4; ++r) {
            ht[(quad * 4 + r) * 72 + col] = __float2half(fmaxf(acc[r] + bias, 0.f));
        }
    }
    __syncthreads();

    // ---- layer 2: A-frags straight from the LDS tile ----
    f16x8 h0 = *(const f16x8*)(ht + m * 72 + (quad << 3));
    f16x8 h1 = *(const f16x8*)(ht + m * 72 + 32 + (quad << 3));
#pragma unroll
    for (int ct = 0; ct < 6; ++ct) {
        f32x4 acc = {0.f, 0.f, 0.f, 0.f};
        f16x8 b0 = *(const f16x8*)(W2f + ((size_t)(ct * 2 + 0) * 64 + lane) * 8);
        f16x8 b1v = *(const f16x8*)(W2f + ((size_t)(ct * 2 + 1) * 64 + lane) * 8);
        acc = __builtin_amdgcn_mfma_f32_16x16x32_f16(h0, b0, acc, 0, 0, 0);
        acc = __builtin_amdgcn_mfma_f32_16x16x32_f16(h1, b1v, acc, 0, 0, 0);
        int seg = ct >> 1;                      // wave-uniform
        int c = ((ct & 1) << 4) | m;            // col within segment
#pragma unroll
        for (int r = 0; r < 4; ++r) {
            int n = node0 + (quad << 2) + r;
            if (n >= nnodes) continue;
            float v = acc[r];
            if (seg == 0)      P0[(size_t)n * 32 + c] = v + b2[c];
            else if (seg == 1) G1[(size_t)n * 32 + c] = __float2half(v);
            else               G2[(size_t)n * 32 + c] = __float2half(v);
        }
    }
}

extern "C" void kernel_launch(void* const* d_in, const int* in_sizes, int n_in,
                              void* d_out, int out_size, void* d_ws, size_t ws_size,
                              hipStream_t stream) {
    const float* x  = (const float*)d_in[0];
    const int*   ei = (const int*)d_in[1];
    const float* W1 = (const float*)d_in[2];
    const float* b1 = (const float*)d_in[3];
    const float* W2 = (const float*)d_in[4];
    const float* b2 = (const float*)d_in[5];
    float* out = (float*)d_out;

    const int NN = N_NODES_C;
    const int NE = N_EDGES_C;
    const size_t HFEAT_BYTES = (size_t)NN * 64 * sizeof(__half);
    const size_t H32_BYTES = (size_t)NN * 32 * sizeof(__half);

    char* ws = (char*)d_ws;
    size_t off = 0;
    auto alloc = [&](size_t bytes) -> void* {
        void* p = ws + off;
        off += (bytes + 255) & ~(size_t)255;
        return p;
    };
    int*    bucket_cnt  = (int*)alloc((size_t)NBUK * 4);
    int*    bucket_base = (int*)alloc((size_t)(NBUK + 1) * 4);
    int*    bucket_next = (int*)alloc((size_t)NBUK * 4);
    int*    rowptr      = (int*)alloc((size_t)(NN + 1) * 4);
    float*  dis         = (float*)alloc((size_t)NN * 4);
    int2*   staged      = (int2*)alloc((size_t)NE * 8);
    int2*   colw        = (int2*)alloc((size_t)NE * 8);
    __half* xh          = (__half*)alloc(HFEAT_BYTES);
    __half* T1h         = (__half*)alloc(HFEAT_BYTES);   // layer1: T1; layer2: G1
    __half* T2h         = (__half*)alloc(HFEAT_BYTES);   // layer1: T2; layer2: G2
    __half* Qh          = (__half*)alloc(H32_BYTES);
    float*  P0          = (float*)alloc((size_t)NN * 32 * 4);
    __half* W1f         = (__half*)alloc((size_t)4 * 6 * 64 * 8 * 2);   // 24 KB
    __half* W2f         = (__half*)alloc((size_t)6 * 2 * 64 * 8 * 2);   // 12 KB

    const int PROPB = (NN + 31) / 32;    // 3125 blocks, 32 nodes each
    const int CONV4 = NN * 64 / 4;
    const int CONVB = (CONV4 + 255) / 256;
    const int BINB = (NE + CHUNK - 1) / CHUNK;
    const int GEMMB = (NN + 63) / 64;

    // ---- CSR build (bucket-atomic) + weight packing + x->fp16 ----
    hipMemsetAsync(bucket_cnt, 0, (size_t)NBUK * 4, stream);
    hist_f2h<<<BINB + CONVB, 256, 0, stream>>>(ei, bucket_cnt, x, xh, NE, CONV4, BINB);
    bucket_scan<<<1, 256, 0, stream>>>(bucket_cnt, bucket_base, bucket_next, NBUK);
    bin_stage<<<BINB, 256, 0, stream>>>(ei, bucket_next, staged, NE);
    bin_count<<<NBUK, 256, 0, stream>>>(staged, bucket_base, rowptr, dis, NN, NE);
    bin_place<<<NBUK, 256, 0, stream>>>(staged, rowptr, dis, colw, NN);
    fold_wf<<<(18432 + 255) / 256, 256, 0, stream>>>(W1, W2, W1f, W2f);

    // ---- layer 1 props, then fused both-layer GEMM ----
    prop_gather_h<<<PROPB, 256, 0, stream>>>(xh, rowptr, colw, T1h, NN);
    prop_gather_h<<<PROPB, 256, 0, stream>>>(T1h, rowptr, colw, T2h, NN);
    gemm_fused<<<GEMMB, 256, 0, stream>>>(xh, T1h, T2h, W1f, b1, W2f, b2, P0, T1h, T2h, NN);

    // ---- layer 2 (factored): out = P0 + prop(G1 + prop(G2)) ----
    prop_gather32<false><<<PROPB, 256, 0, stream>>>(T2h, rowptr, colw, T1h, Qh, NN);
    prop_gather32<true><<<PROPB, 256, 0, stream>>>(Qh, rowptr, colw, P0, out, NN);
}

// Round 18
// 245.022 us; speedup vs baseline: 6.9490x; 1.0451x over previous
//
#include <hip/hip_runtime.h>
#include <hip/hip_fp16.h>

#define N_NODES_C 100000
#define N_EDGES_C 1200000
#define NBUK ((N_NODES_C + 255) >> 8)   // 391 buckets of 256 nodes
#define CHUNK 4096                       // edges per binning block

typedef _Float16 f16x8 __attribute__((ext_vector_type(8)));
typedef float f32x4 __attribute__((ext_vector_type(4)));

// staged entry: col (bits 0..16) | bucket-relative row (bits 17..24)
#define PACK(r8, c) ((c) | ((r8) << 17))
#define UNPACK_C(v) ((v) & 0x1FFFF)
#define UNPACK_R(v) ((v) >> 17)

// ---------- merged: bucket histogram (blocks 0..histB-1) + fp32->fp16 convert ----------
__global__ __launch_bounds__(256) void hist_f2h(const int* __restrict__ ei,
                                                int* __restrict__ bucket_cnt,
                                                const float* __restrict__ x,
                                                __half* __restrict__ xh,
                                                int nedges, int n4, int histB) {
    __shared__ int cnt[NBUK];
    const int tid = threadIdx.x;
    if (blockIdx.x < histB) {
        const int base = blockIdx.x * CHUNK;
        const int nloc = min(CHUNK, nedges - base);
        for (int i = tid; i < NBUK; i += 256) cnt[i] = 0;
        __syncthreads();
        for (int i = tid; i < nloc; i += 256) atomicAdd(&cnt[ei[base + i] >> 8], 1);
        __syncthreads();
        for (int b = tid; b < NBUK; b += 256) {
            int n = cnt[b];
            if (n) atomicAdd(&bucket_cnt[b], n);
        }
    } else {
        int i = (blockIdx.x - histB) * 256 + tid;
        if (i < n4) {
            float4 v = ((const float4*)x)[i];
            __half2 tmp[2];
            tmp[0] = __floats2half2_rn(v.x, v.y);
            tmp[1] = __floats2half2_rn(v.z, v.w);
            ((float2*)xh)[i] = *(float2*)tmp;
        }
    }
}

// ---------- merged: block 0 scans bucket counts; blocks 1.. pack MFMA weights ----------
__global__ __launch_bounds__(256) void scan_fold(const int* __restrict__ bucket_cnt,
                                                 int* __restrict__ bucket_base,
                                                 int* __restrict__ bucket_next, int nb,
                                                 const float* __restrict__ W1,
                                                 const float* __restrict__ W2,
                                                 __half* __restrict__ W1f,
                                                 __half* __restrict__ W2f) {
    const int tid = threadIdx.x;
    if (blockIdx.x == 0) {
        __shared__ int s[256];
        int a0 = (2 * tid < nb) ? bucket_cnt[2 * tid] : 0;
        int a1 = (2 * tid + 1 < nb) ? bucket_cnt[2 * tid + 1] : 0;
        s[tid] = a0 + a1;
        __syncthreads();
        for (int off = 1; off < 256; off <<= 1) {
            int v = s[tid];
            int add = (tid >= off) ? s[tid - off] : 0;
            __syncthreads();
            s[tid] = v + add;
            __syncthreads();
        }
        int excl = (tid > 0) ? s[tid - 1] : 0;
        if (2 * tid < nb) { bucket_base[2 * tid] = excl; bucket_next[2 * tid] = excl; }
        if (2 * tid + 1 < nb) { bucket_base[2 * tid + 1] = excl + a0; bucket_next[2 * tid + 1] = excl + a0; }
        if (tid == 255) bucket_base[nb] = s[255];
        return;
    }
    int i = (blockIdx.x - 1) * 256 + tid;
    if (i < 12288) {                       // layer-1: [4 ct][6 kh][64 lane][8 j]
        int j = i & 7;
        int lane = (i >> 3) & 63;
        int rest = i >> 9;
        int kh = rest % 6;
        int ct = rest / 6;
        int term = kh >> 1;
        int k = ((kh & 1) << 5) | ((lane >> 4) << 3) | j;
        int c = (ct << 4) | (lane & 15);
        float w0 = W1[k * 64 + c];
        float w1 = W1[4096 + k * 64 + c];
        float w2 = W1[2 * 4096 + k * 64 + c];
        float v = (term == 0) ? (w0 - w2) : ((term == 1) ? w1 : 2.0f * w2);
        W1f[i] = __float2half(v);
    } else if (i < 12288 + 6144) {         // layer-2: [6 ct][2 kh][64 lane][8 j]
        int ii = i - 12288;
        int j = ii & 7;
        int lane = (ii >> 3) & 63;
        int rest = ii >> 9;
        int kh = rest & 1;
        int ct = rest >> 1;
        int k = (kh << 5) | ((lane >> 4) << 3) | j;
        int cg = ct * 16 + (lane & 15);
        int seg = cg >> 5;
        int c = cg & 31;
        float w0 = W2[k * 32 + c];
        float w1 = W2[2048 + k * 32 + c];
        float w2 = W2[2 * 2048 + k * 32 + c];
        float v = (seg == 0) ? (w0 - w2) : ((seg == 1) ? w1 : 2.0f * w2);
        W2f[ii] = __float2half(v);
    }
}

// ---------- phase B: LDS-binned staging grouped by 256-node bucket (packed int) ----------
__global__ __launch_bounds__(256) void bin_stage(const int* __restrict__ ei,
                                                 int* __restrict__ bucket_next,
                                                 int* __restrict__ staged, int nedges) {
    __shared__ int cnt[NBUK];
    __shared__ int ofs[NBUK];
    __shared__ int run[NBUK];
    __shared__ int gbase[NBUK];
    __shared__ int ssum[256];
    __shared__ int2 sedge[CHUNK];
    const int tid = threadIdx.x;
    const int base = blockIdx.x * CHUNK;
    const int nloc = min(CHUNK, nedges - base);

    for (int i = tid; i < NBUK; i += 256) { cnt[i] = 0; run[i] = 0; }
    __syncthreads();

    int r[16], c[16];
#pragma unroll
    for (int k = 0; k < 16; ++k) {
        int loc = tid + k * 256;
        bool ok = loc < nloc;
        int idx = base + loc;
        r[k] = ok ? ei[idx] : -1;
        c[k] = ok ? ei[nedges + idx] : 0;
        if (ok) atomicAdd(&cnt[r[k] >> 8], 1);
    }
    __syncthreads();

    int a0 = (2 * tid < NBUK) ? cnt[2 * tid] : 0;
    int a1 = (2 * tid + 1 < NBUK) ? cnt[2 * tid + 1] : 0;
    ssum[tid] = a0 + a1;
    __syncthreads();
    for (int off = 1; off < 256; off <<= 1) {
        int v = ssum[tid];
        int add = (tid >= off) ? ssum[tid - off] : 0;
        __syncthreads();
        ssum[tid] = v + add;
        __syncthreads();
    }
    int excl = (tid > 0) ? ssum[tid - 1] : 0;
    if (2 * tid < NBUK) ofs[2 * tid] = excl;
    if (2 * tid + 1 < NBUK) ofs[2 * tid + 1] = excl + a0;
    __syncthreads();

#pragma unroll
    for (int k = 0; k < 16; ++k) {
        if (r[k] >= 0) {
            int b = r[k] >> 8;
            int p = atomicAdd(&run[b], 1);
            sedge[ofs[b] + p] = make_int2(r[k], c[k]);
        }
    }
    __syncthreads();

    for (int b = tid; b < NBUK; b += 256) {
        int n = cnt[b];
        gbase[b] = n ? atomicAdd(&bucket_next[b], n) : 0;
    }
    __syncthreads();

    for (int i = tid; i < nloc; i += 256) {
        int2 e = sedge[i];
        int b = e.x >> 8;
        staged[gbase[b] + (i - ofs[b])] = PACK(e.x & 255, e.y);
    }
}

// ---------- phase C1: per-bucket degree count -> rowptr slice + deg_inv_sqrt ----------
__global__ __launch_bounds__(256) void bin_count(const int* __restrict__ staged,
                                                 const int* __restrict__ bucket_base,
                                                 int* __restrict__ rowptr, float* __restrict__ dis,
                                                 int nnodes, int nedges) {
    __shared__ int deg[256];
    __shared__ int ssum[256];
    const int b = blockIdx.x;
    const int n0 = b << 8;
    const int nend = min(n0 + 256, nnodes);
    const int nloc = nend - n0;
    const int tid = threadIdx.x;
    deg[tid] = 0;
    __syncthreads();
    const int ebase = bucket_base[b];
    const int ecount = bucket_base[b + 1] - ebase;
    for (int i = tid; i < ecount; i += 256) {
        atomicAdd(&deg[UNPACK_R(staged[ebase + i])], 1);
    }
    __syncthreads();
    int d = deg[tid];
    if (tid < nloc) {
        float df = (float)d;
        dis[n0 + tid] = (d > 0) ? (1.0f / sqrtf(fmaxf(df, 1.f))) : 0.f;
    }
    ssum[tid] = d;
    __syncthreads();
    for (int off = 1; off < 256; off <<= 1) {
        int v = ssum[tid];
        int add = (tid >= off) ? ssum[tid - off] : 0;
        __syncthreads();
        ssum[tid] = v + add;
        __syncthreads();
    }
    int excl = (tid > 0) ? ssum[tid - 1] : 0;
    if (tid < nloc) rowptr[n0 + tid] = ebase + excl;
    if (b == NBUK - 1 && tid == 0) rowptr[nnodes] = nedges;
}

// ---------- phase C2: per-bucket exact CSR placement + norm weight ----------
__global__ __launch_bounds__(256) void bin_place(const int* __restrict__ staged,
                                                 const int* __restrict__ rowptr,
                                                 const float* __restrict__ dis,
                                                 int2* __restrict__ colw, int nnodes) {
    __shared__ int rp[256];
    __shared__ int nx[256];
    __shared__ float dl[256];
    const int b = blockIdx.x;
    const int n0 = b << 8;
    const int nend = min(n0 + 256, nnodes);
    const int nloc = nend - n0;
    const int tid = threadIdx.x;
    if (tid < nloc) {
        rp[tid] = rowptr[n0 + tid];
        dl[tid] = dis[n0 + tid];
    }
    nx[tid] = 0;
    __syncthreads();
    const int ebase = rowptr[n0];
    const int ecount = rowptr[nend] - ebase;
    for (int i = tid; i < ecount; i += 256) {
        int v = staged[ebase + i];
        int col = UNPACK_C(v);
        int rrel = UNPACK_R(v);
        int p = atomicAdd(&nx[rrel], 1);
        float w = -dl[rrel] * dis[col];
        colw[rp[rrel] + p] = make_int2(col, __float_as_int(w));
    }
}

// ---------- prop64: 8-lane groups, 8 nodes/wave, serial walk unroll x4 ----------
__global__ __launch_bounds__(256) void prop_gather_h(const __half* __restrict__ t,
                                                     const int* __restrict__ rowptr,
                                                     const int2* __restrict__ colw,
                                                     __half* __restrict__ out, int nnodes) {
    int grp = threadIdx.x >> 3;          // 0..31 within block
    int ln = threadIdx.x & 7;            // 16B chunk: ch 8*ln .. 8*ln+7
    int node = blockIdx.x * 32 + grp;
    if (node >= nnodes) return;
    int s = rowptr[node];
    int e = rowptr[node + 1];
    float acc[8] = {0.f, 0.f, 0.f, 0.f, 0.f, 0.f, 0.f, 0.f};
    int i = s;
    for (; i + 3 < e; i += 4) {
        int2 cw0 = colw[i];
        int2 cw1 = colw[i + 1];
        int2 cw2 = colw[i + 2];
        int2 cw3 = colw[i + 3];
        float4 r0 = ((const float4*)(t + (size_t)cw0.x * 64))[ln];
        float4 r1 = ((const float4*)(t + (size_t)cw1.x * 64))[ln];
        float4 r2 = ((const float4*)(t + (size_t)cw2.x * 64))[ln];
        float4 r3 = ((const float4*)(t + (size_t)cw3.x * 64))[ln];
        float w0 = __int_as_float(cw0.y);
        float w1 = __int_as_float(cw1.y);
        float w2 = __int_as_float(cw2.y);
        float w3 = __int_as_float(cw3.y);
        const __half2* h0 = (const __half2*)&r0;
        const __half2* h1 = (const __half2*)&r1;
        const __half2* h2 = (const __half2*)&r2;
        const __half2* h3 = (const __half2*)&r3;
#pragma unroll
        for (int q = 0; q < 4; ++q) {
            float2 f0 = __half22float2(h0[q]);
            float2 f1 = __half22float2(h1[q]);
            float2 f2 = __half22float2(h2[q]);
            float2 f3 = __half22float2(h3[q]);
            acc[2 * q + 0] += w0 * f0.x + w1 * f1.x + w2 * f2.x + w3 * f3.x;
            acc[2 * q + 1] += w0 * f0.y + w1 * f1.y + w2 * f2.y + w3 * f3.y;
        }
    }
    for (; i < e; ++i) {
        int2 cw0 = colw[i];
        float w0 = __int_as_float(cw0.y);
        float4 r0 = ((const float4*)(t + (size_t)cw0.x * 64))[ln];
        const __half2* h0 = (const __half2*)&r0;
#pragma unroll
        for (int q = 0; q < 4; ++q) {
            float2 f0 = __half22float2(h0[q]);
            acc[2 * q + 0] += w0 * f0.x;
            acc[2 * q + 1] += w0 * f0.y;
        }
    }
    __half2 tmp[4];
    tmp[0] = __floats2half2_rn(acc[0], acc[1]);
    tmp[1] = __floats2half2_rn(acc[2], acc[3]);
    tmp[2] = __floats2half2_rn(acc[4], acc[5]);
    tmp[3] = __floats2half2_rn(acc[6], acc[7]);
    ((float4*)(out + (size_t)node * 64))[ln] = *(float4*)tmp;
}

// ---------- prop32: 8-lane groups, 8 nodes/wave, unroll x4; fused add-input ----------
template <bool F32OUT>
__global__ __launch_bounds__(256) void prop_gather32(const __half* __restrict__ t,
                                                     const int* __restrict__ rowptr,
                                                     const int2* __restrict__ colw,
                                                     const void* __restrict__ addin,
                                                     void* __restrict__ outv, int nnodes) {
    int grp = threadIdx.x >> 3;          // 0..31 within block
    int ln = threadIdx.x & 7;            // 8B chunk: ch 4*ln .. 4*ln+3
    int node = blockIdx.x * 32 + grp;
    if (node >= nnodes) return;
    int s = rowptr[node];
    int e = rowptr[node + 1];
    float acc[4] = {0.f, 0.f, 0.f, 0.f};
    int i = s;
    for (; i + 3 < e; i += 4) {
        int2 cw0 = colw[i];
        int2 cw1 = colw[i + 1];
        int2 cw2 = colw[i + 2];
        int2 cw3 = colw[i + 3];
        float2 r0 = ((const float2*)(t + (size_t)cw0.x * 32))[ln];
        float2 r1 = ((const float2*)(t + (size_t)cw1.x * 32))[ln];
        float2 r2 = ((const float2*)(t + (size_t)cw2.x * 32))[ln];
        float2 r3 = ((const float2*)(t + (size_t)cw3.x * 32))[ln];
        float w0 = __int_as_float(cw0.y);
        float w1 = __int_as_float(cw1.y);
        float w2 = __int_as_float(cw2.y);
        float w3 = __int_as_float(cw3.y);
        const __half2* h0 = (const __half2*)&r0;
        const __half2* h1 = (const __half2*)&r1;
        const __half2* h2 = (const __half2*)&r2;
        const __half2* h3 = (const __half2*)&r3;
#pragma unroll
        for (int q = 0; q < 2; ++q) {
            float2 f0 = __half22float2(h0[q]);
            float2 f1 = __half22float2(h1[q]);
            float2 f2 = __half22float2(h2[q]);
            float2 f3 = __half22float2(h3[q]);
            acc[2 * q + 0] += w0 * f0.x + w1 * f1.x + w2 * f2.x + w3 * f3.x;
            acc[2 * q + 1] += w0 * f0.y + w1 * f1.y + w2 * f2.y + w3 * f3.y;
        }
    }
    for (; i < e; ++i) {
        int2 cw0 = colw[i];
        float w0 = __int_as_float(cw0.y);
        float2 r0 = ((const float2*)(t + (size_t)cw0.x * 32))[ln];
        const __half2* h0 = (const __half2*)&r0;
#pragma unroll
        for (int q = 0; q < 2; ++q) {
            float2 f0 = __half22float2(h0[q]);
            acc[2 * q + 0] += w0 * f0.x;
            acc[2 * q + 1] += w0 * f0.y;
        }
    }
    if (F32OUT) {
        const float* add = (const float*)addin;
        float* out = (float*)outv;
        float4 a = ((const float4*)(add + (size_t)node * 32))[ln];
        a.x += acc[0]; a.y += acc[1]; a.z += acc[2]; a.w += acc[3];
        ((float4*)(out + (size_t)node * 32))[ln] = a;
    } else {
        const __half* add = (const __half*)addin;
        __half* out = (__half*)outv;
        float2 raw = ((const float2*)(add + (size_t)node * 32))[ln];
        const __half2* hp = (const __half2*)&raw;
        float2 a0 = __half22float2(hp[0]);
        float2 a1 = __half22float2(hp[1]);
        __half2 tmp[2];
        tmp[0] = __floats2half2_rn(acc[0] + a0.x, acc[1] + a0.y);
        tmp[1] = __floats2half2_rn(acc[2] + a1.x, acc[3] + a1.y);
        ((float2*)(out + (size_t)node * 32))[ln] = *(float2*)tmp;
    }
}

// ---------- FUSED both-layer MFMA GEMM ----------
__global__ __launch_bounds__(256) void gemm_fused(const __half* __restrict__ A0,
                                                  const __half* __restrict__ A1,
                                                  const __half* __restrict__ A2,
                                                  const __half* __restrict__ W1f,
                                                  const float* __restrict__ b1,
                                                  const __half* __restrict__ W2f,
                                                  const float* __restrict__ b2,
                                                  float* __restrict__ P0,
                                                  __half* __restrict__ G1,
                                                  __half* __restrict__ G2, int nnodes) {
    __shared__ __align__(16) __half htile[4][16 * 72];   // 9 KB
    const int wave = threadIdx.x >> 6;
    const int lane = threadIdx.x & 63;
    const int node0 = blockIdx.x * 64 + wave * 16;
    const int m = lane & 15;
    const int quad = lane >> 4;
    int arow = node0 + m;
    if (arow >= nnodes) arow = nnodes - 1;   // clamp: garbage rows never stored globally

    // ---- layer 1 ----
    const __half* Ap[3] = {A0, A1, A2};
    f16x8 a[6];
#pragma unroll
    for (int kh = 0; kh < 6; ++kh) {
        const __half* A = Ap[kh >> 1];
        a[kh] = *(const f16x8*)(A + (size_t)arow * 64 + ((kh & 1) << 5) + (quad << 3));
    }
    __half* ht = htile[wave];
#pragma unroll
    for (int ct = 0; ct < 4; ++ct) {
        f32x4 acc = {0.f, 0.f, 0.f, 0.f};
#pragma unroll
        for (int kh = 0; kh < 6; ++kh) {
            f16x8 b = *(const f16x8*)(W1f + ((size_t)(ct * 6 + kh) * 64 + lane) * 8);
            acc = __builtin_amdgcn_mfma_f32_16x16x32_f16(a[kh], b, acc, 0, 0, 0);
        }
        int col = (ct << 4) | m;
        float bias = b1[col];
#pragma unroll
        for (int r = 0; r < 4; ++r) {
            ht[(quad * 4 + r) * 72 + col] = __float2half(fmaxf(acc[r] + bias, 0.f));
        }
    }
    __syncthreads();

    // ---- layer 2: A-frags straight from the LDS tile ----
    f16x8 h0 = *(const f16x8*)(ht + m * 72 + (quad << 3));
    f16x8 h1 = *(const f16x8*)(ht + m * 72 + 32 + (quad << 3));
#pragma unroll
    for (int ct = 0; ct < 6; ++ct) {
        f32x4 acc = {0.f, 0.f, 0.f, 0.f};
        f16x8 b0 = *(const f16x8*)(W2f + ((size_t)(ct * 2 + 0) * 64 + lane) * 8);
        f16x8 b1v = *(const f16x8*)(W2f + ((size_t)(ct * 2 + 1) * 64 + lane) * 8);
        acc = __builtin_amdgcn_mfma_f32_16x16x32_f16(h0, b0, acc, 0, 0, 0);
        acc = __builtin_amdgcn_mfma_f32_16x16x32_f16(h1, b1v, acc, 0, 0, 0);
        int seg = ct >> 1;                      // wave-uniform
        int c = ((ct & 1) << 4) | m;            // col within segment
#pragma unroll
        for (int r = 0; r < 4; ++r) {
            int n = node0 + (quad << 2) + r;
            if (n >= nnodes) continue;
            float v = acc[r];
            if (seg == 0)      P0[(size_t)n * 32 + c] = v + b2[c];
            else if (seg == 1) G1[(size_t)n * 32 + c] = __float2half(v);
            else               G2[(size_t)n * 32 + c] = __float2half(v);
        }
    }
}

extern "C" void kernel_launch(void* const* d_in, const int* in_sizes, int n_in,
                              void* d_out, int out_size, void* d_ws, size_t ws_size,
                              hipStream_t stream) {
    const float* x  = (const float*)d_in[0];
    const int*   ei = (const int*)d_in[1];
    const float* W1 = (const float*)d_in[2];
    const float* b1 = (const float*)d_in[3];
    const float* W2 = (const float*)d_in[4];
    const float* b2 = (const float*)d_in[5];
    float* out = (float*)d_out;

    const int NN = N_NODES_C;
    const int NE = N_EDGES_C;
    const size_t HFEAT_BYTES = (size_t)NN * 64 * sizeof(__half);
    const size_t H32_BYTES = (size_t)NN * 32 * sizeof(__half);

    char* ws = (char*)d_ws;
    size_t off = 0;
    auto alloc = [&](size_t bytes) -> void* {
        void* p = ws + off;
        off += (bytes + 255) & ~(size_t)255;
        return p;
    };
    int*    bucket_cnt  = (int*)alloc((size_t)NBUK * 4);
    int*    bucket_base = (int*)alloc((size_t)(NBUK + 1) * 4);
    int*    bucket_next = (int*)alloc((size_t)NBUK * 4);
    int*    rowptr      = (int*)alloc((size_t)(NN + 1) * 4);
    float*  dis         = (float*)alloc((size_t)NN * 4);
    int*    staged      = (int*)alloc((size_t)NE * 4);
    int2*   colw        = (int2*)alloc((size_t)NE * 8);
    __half* xh          = (__half*)alloc(HFEAT_BYTES);
    __half* T1h         = (__half*)alloc(HFEAT_BYTES);   // layer1: T1; layer2: G1
    __half* T2h         = (__half*)alloc(HFEAT_BYTES);   // layer1: T2; layer2: G2
    __half* Qh          = (__half*)alloc(H32_BYTES);
    float*  P0          = (float*)alloc((size_t)NN * 32 * 4);
    __half* W1f         = (__half*)alloc((size_t)4 * 6 * 64 * 8 * 2);   // 24 KB
    __half* W2f         = (__half*)alloc((size_t)6 * 2 * 64 * 8 * 2);   // 12 KB

    const int PROPB = (NN + 31) / 32;    // 3125 blocks, 32 nodes each
    const int CONV4 = NN * 64 / 4;
    const int CONVB = (CONV4 + 255) / 256;
    const int BINB = (NE + CHUNK - 1) / CHUNK;
    const int GEMMB = (NN + 63) / 64;
    const int FOLDB = 1 + (18432 + 255) / 256;

    // ---- CSR build (bucket-atomic) + weight packing + x->fp16 ----
    hipMemsetAsync(bucket_cnt, 0, (size_t)NBUK * 4, stream);
    hist_f2h<<<BINB + CONVB, 256, 0, stream>>>(ei, bucket_cnt, x, xh, NE, CONV4, BINB);
    scan_fold<<<FOLDB, 256, 0, stream>>>(bucket_cnt, bucket_base, bucket_next, NBUK,
                                         W1, W2, W1f, W2f);
    bin_stage<<<BINB, 256, 0, stream>>>(ei, bucket_next, staged, NE);
    bin_count<<<NBUK, 256, 0, stream>>>(staged, bucket_base, rowptr, dis, NN, NE);
    bin_place<<<NBUK, 256, 0, stream>>>(staged, rowptr, dis, colw, NN);

    // ---- layer 1 props, then fused both-layer GEMM ----
    prop_gather_h<<<PROPB, 256, 0, stream>>>(xh, rowptr, colw, T1h, NN);
    prop_gather_h<<<PROPB, 256, 0, stream>>>(T1h, rowptr, colw, T2h, NN);
    gemm_fused<<<GEMMB, 256, 0, stream>>>(xh, T1h, T2h, W1f, b1, W2f, b2, P0, T1h, T2h, NN);

    // ---- layer 2 (factored): out = P0 + prop(G1 + prop(G2)) ----
    prop_gather32<false><<<PROPB, 256, 0, stream>>>(T2h, rowptr, colw, T1h, Qh, NN);
    prop_gather32<true><<<PROPB, 256, 0, stream>>>(Qh, rowptr, colw, P0, out, NN);
}

// Round 19
// 244.421 us; speedup vs baseline: 6.9661x; 1.0025x over previous
//
#include <hip/hip_runtime.h>
#include <hip/hip_fp16.h>

#define N_NODES_C 100000
#define N_EDGES_C 1200000
#define NBUK ((N_NODES_C + 255) >> 8)   // 391 buckets of 256 nodes
#define CHUNK 4096                       // edges per binning block

typedef _Float16 f16x8 __attribute__((ext_vector_type(8)));
typedef float f32x4 __attribute__((ext_vector_type(4)));

// staged entry: col (bits 0..16) | bucket-relative row (bits 17..24)
#define PACK(r8, c) ((c) | ((r8) << 17))
#define UNPACK_C(v) ((v) & 0x1FFFF)
#define UNPACK_R(v) ((v) >> 17)

// ---------- merged: bucket histogram (blocks 0..histB-1) + fp32->fp16 convert ----------
__global__ __launch_bounds__(256) void hist_f2h(const int* __restrict__ ei,
                                                int* __restrict__ bucket_cnt,
                                                const float* __restrict__ x,
                                                __half* __restrict__ xh,
                                                int nedges, int n4, int histB) {
    __shared__ int cnt[NBUK];
    const int tid = threadIdx.x;
    if (blockIdx.x < histB) {
        const int base = blockIdx.x * CHUNK;
        const int nloc = min(CHUNK, nedges - base);
        for (int i = tid; i < NBUK; i += 256) cnt[i] = 0;
        __syncthreads();
        for (int i = tid; i < nloc; i += 256) atomicAdd(&cnt[ei[base + i] >> 8], 1);
        __syncthreads();
        for (int b = tid; b < NBUK; b += 256) {
            int n = cnt[b];
            if (n) atomicAdd(&bucket_cnt[b], n);
        }
    } else {
        int i = (blockIdx.x - histB) * 256 + tid;
        if (i < n4) {
            float4 v = ((const float4*)x)[i];
            __half2 tmp[2];
            tmp[0] = __floats2half2_rn(v.x, v.y);
            tmp[1] = __floats2half2_rn(v.z, v.w);
            ((float2*)xh)[i] = *(float2*)tmp;
        }
    }
}

// ---------- merged: block 0 scans bucket counts; blocks 1.. pack MFMA weights ----------
__global__ __launch_bounds__(256) void scan_fold(const int* __restrict__ bucket_cnt,
                                                 int* __restrict__ bucket_base,
                                                 int* __restrict__ bucket_next, int nb,
                                                 const float* __restrict__ W1,
                                                 const float* __restrict__ W2,
                                                 __half* __restrict__ W1f,
                                                 __half* __restrict__ W2f) {
    const int tid = threadIdx.x;
    if (blockIdx.x == 0) {
        __shared__ int s[256];
        int a0 = (2 * tid < nb) ? bucket_cnt[2 * tid] : 0;
        int a1 = (2 * tid + 1 < nb) ? bucket_cnt[2 * tid + 1] : 0;
        s[tid] = a0 + a1;
        __syncthreads();
        for (int off = 1; off < 256; off <<= 1) {
            int v = s[tid];
            int add = (tid >= off) ? s[tid - off] : 0;
            __syncthreads();
            s[tid] = v + add;
            __syncthreads();
        }
        int excl = (tid > 0) ? s[tid - 1] : 0;
        if (2 * tid < nb) { bucket_base[2 * tid] = excl; bucket_next[2 * tid] = excl; }
        if (2 * tid + 1 < nb) { bucket_base[2 * tid + 1] = excl + a0; bucket_next[2 * tid + 1] = excl + a0; }
        if (tid == 255) bucket_base[nb] = s[255];
        return;
    }
    int i = (blockIdx.x - 1) * 256 + tid;
    if (i < 12288) {                       // layer-1: [4 ct][6 kh][64 lane][8 j]
        int j = i & 7;
        int lane = (i >> 3) & 63;
        int rest = i >> 9;
        int kh = rest % 6;
        int ct = rest / 6;
        int term = kh >> 1;
        int k = ((kh & 1) << 5) | ((lane >> 4) << 3) | j;
        int c = (ct << 4) | (lane & 15);
        float w0 = W1[k * 64 + c];
        float w1 = W1[4096 + k * 64 + c];
        float w2 = W1[2 * 4096 + k * 64 + c];
        float v = (term == 0) ? (w0 - w2) : ((term == 1) ? w1 : 2.0f * w2);
        W1f[i] = __float2half(v);
    } else if (i < 12288 + 6144) {         // layer-2: [6 ct][2 kh][64 lane][8 j]
        int ii = i - 12288;
        int j = ii & 7;
        int lane = (ii >> 3) & 63;
        int rest = ii >> 9;
        int kh = rest & 1;
        int ct = rest >> 1;
        int k = (kh << 5) | ((lane >> 4) << 3) | j;
        int cg = ct * 16 + (lane & 15);
        int seg = cg >> 5;
        int c = cg & 31;
        float w0 = W2[k * 32 + c];
        float w1 = W2[2048 + k * 32 + c];
        float w2 = W2[2 * 2048 + k * 32 + c];
        float v = (seg == 0) ? (w0 - w2) : ((seg == 1) ? w1 : 2.0f * w2);
        W2f[ii] = __float2half(v);
    }
}

// ---------- phase B: LDS-binned staging grouped by 256-node bucket (packed int) ----------
__global__ __launch_bounds__(256) void bin_stage(const int* __restrict__ ei,
                                                 int* __restrict__ bucket_next,
                                                 int* __restrict__ staged, int nedges) {
    __shared__ int cnt[NBUK];
    __shared__ int ofs[NBUK];
    __shared__ int run[NBUK];
    __shared__ int gbase[NBUK];
    __shared__ int ssum[256];
    __shared__ int2 sedge[CHUNK];
    const int tid = threadIdx.x;
    const int base = blockIdx.x * CHUNK;
    const int nloc = min(CHUNK, nedges - base);

    for (int i = tid; i < NBUK; i += 256) { cnt[i] = 0; run[i] = 0; }
    __syncthreads();

    int r[16], c[16];
#pragma unroll
    for (int k = 0; k < 16; ++k) {
        int loc = tid + k * 256;
        bool ok = loc < nloc;
        int idx = base + loc;
        r[k] = ok ? ei[idx] : -1;
        c[k] = ok ? ei[nedges + idx] : 0;
        if (ok) atomicAdd(&cnt[r[k] >> 8], 1);
    }
    __syncthreads();

    int a0 = (2 * tid < NBUK) ? cnt[2 * tid] : 0;
    int a1 = (2 * tid + 1 < NBUK) ? cnt[2 * tid + 1] : 0;
    ssum[tid] = a0 + a1;
    __syncthreads();
    for (int off = 1; off < 256; off <<= 1) {
        int v = ssum[tid];
        int add = (tid >= off) ? ssum[tid - off] : 0;
        __syncthreads();
        ssum[tid] = v + add;
        __syncthreads();
    }
    int excl = (tid > 0) ? ssum[tid - 1] : 0;
    if (2 * tid < NBUK) ofs[2 * tid] = excl;
    if (2 * tid + 1 < NBUK) ofs[2 * tid + 1] = excl + a0;
    __syncthreads();

#pragma unroll
    for (int k = 0; k < 16; ++k) {
        if (r[k] >= 0) {
            int b = r[k] >> 8;
            int p = atomicAdd(&run[b], 1);
            sedge[ofs[b] + p] = make_int2(r[k], c[k]);
        }
    }
    __syncthreads();

    for (int b = tid; b < NBUK; b += 256) {
        int n = cnt[b];
        gbase[b] = n ? atomicAdd(&bucket_next[b], n) : 0;
    }
    __syncthreads();

    for (int i = tid; i < nloc; i += 256) {
        int2 e = sedge[i];
        int b = e.x >> 8;
        staged[gbase[b] + (i - ofs[b])] = PACK(e.x & 255, e.y);
    }
}

// ---------- phase C1: per-bucket degree count -> rowptr slice + deg_inv_sqrt ----------
__global__ __launch_bounds__(256) void bin_count(const int* __restrict__ staged,
                                                 const int* __restrict__ bucket_base,
                                                 int* __restrict__ rowptr, float* __restrict__ dis,
                                                 int nnodes, int nedges) {
    __shared__ int deg[256];
    __shared__ int ssum[256];
    const int b = blockIdx.x;
    const int n0 = b << 8;
    const int nend = min(n0 + 256, nnodes);
    const int nloc = nend - n0;
    const int tid = threadIdx.x;
    deg[tid] = 0;
    __syncthreads();
    const int ebase = bucket_base[b];
    const int ecount = bucket_base[b + 1] - ebase;
    for (int i = tid; i < ecount; i += 256) {
        atomicAdd(&deg[UNPACK_R(staged[ebase + i])], 1);
    }
    __syncthreads();
    int d = deg[tid];
    if (tid < nloc) {
        float df = (float)d;
        dis[n0 + tid] = (d > 0) ? (1.0f / sqrtf(fmaxf(df, 1.f))) : 0.f;
    }
    ssum[tid] = d;
    __syncthreads();
    for (int off = 1; off < 256; off <<= 1) {
        int v = ssum[tid];
        int add = (tid >= off) ? ssum[tid - off] : 0;
        __syncthreads();
        ssum[tid] = v + add;
        __syncthreads();
    }
    int excl = (tid > 0) ? ssum[tid - 1] : 0;
    if (tid < nloc) rowptr[n0 + tid] = ebase + excl;
    if (b == NBUK - 1 && tid == 0) rowptr[nnodes] = nedges;
}

// ---------- phase C2: per-bucket exact CSR placement + norm weight ----------
__global__ __launch_bounds__(256) void bin_place(const int* __restrict__ staged,
                                                 const int* __restrict__ rowptr,
                                                 const float* __restrict__ dis,
                                                 int2* __restrict__ colw, int nnodes) {
    __shared__ int rp[256];
    __shared__ int nx[256];
    __shared__ float dl[256];
    const int b = blockIdx.x;
    const int n0 = b << 8;
    const int nend = min(n0 + 256, nnodes);
    const int nloc = nend - n0;
    const int tid = threadIdx.x;
    if (tid < nloc) {
        rp[tid] = rowptr[n0 + tid];
        dl[tid] = dis[n0 + tid];
    }
    nx[tid] = 0;
    __syncthreads();
    const int ebase = rowptr[n0];
    const int ecount = rowptr[nend] - ebase;
    for (int i = tid; i < ecount; i += 256) {
        int v = staged[ebase + i];
        int col = UNPACK_C(v);
        int rrel = UNPACK_R(v);
        int p = atomicAdd(&nx[rrel], 1);
        float w = -dl[rrel] * dis[col];
        colw[rp[rrel] + p] = make_int2(col, __float_as_int(w));
    }
}

// ---------- prop64: 8-lane groups, 8 nodes/wave, serial walk unroll x4 ----------
__global__ __launch_bounds__(256) void prop_gather_h(const __half* __restrict__ t,
                                                     const int* __restrict__ rowptr,
                                                     const int2* __restrict__ colw,
                                                     __half* __restrict__ out, int nnodes) {
    int grp = threadIdx.x >> 3;          // 0..31 within block
    int ln = threadIdx.x & 7;            // 16B chunk: ch 8*ln .. 8*ln+7
    int node = blockIdx.x * 32 + grp;
    if (node >= nnodes) return;
    int s = rowptr[node];
    int e = rowptr[node + 1];
    float acc[8] = {0.f, 0.f, 0.f, 0.f, 0.f, 0.f, 0.f, 0.f};
    int i = s;
    for (; i + 3 < e; i += 4) {
        int2 cw0 = colw[i];
        int2 cw1 = colw[i + 1];
        int2 cw2 = colw[i + 2];
        int2 cw3 = colw[i + 3];
        float4 r0 = ((const float4*)(t + (size_t)cw0.x * 64))[ln];
        float4 r1 = ((const float4*)(t + (size_t)cw1.x * 64))[ln];
        float4 r2 = ((const float4*)(t + (size_t)cw2.x * 64))[ln];
        float4 r3 = ((const float4*)(t + (size_t)cw3.x * 64))[ln];
        float w0 = __int_as_float(cw0.y);
        float w1 = __int_as_float(cw1.y);
        float w2 = __int_as_float(cw2.y);
        float w3 = __int_as_float(cw3.y);
        const __half2* h0 = (const __half2*)&r0;
        const __half2* h1 = (const __half2*)&r1;
        const __half2* h2 = (const __half2*)&r2;
        const __half2* h3 = (const __half2*)&r3;
#pragma unroll
        for (int q = 0; q < 4; ++q) {
            float2 f0 = __half22float2(h0[q]);
            float2 f1 = __half22float2(h1[q]);
            float2 f2 = __half22float2(h2[q]);
            float2 f3 = __half22float2(h3[q]);
            acc[2 * q + 0] += w0 * f0.x + w1 * f1.x + w2 * f2.x + w3 * f3.x;
            acc[2 * q + 1] += w0 * f0.y + w1 * f1.y + w2 * f2.y + w3 * f3.y;
        }
    }
    for (; i < e; ++i) {
        int2 cw0 = colw[i];
        float w0 = __int_as_float(cw0.y);
        float4 r0 = ((const float4*)(t + (size_t)cw0.x * 64))[ln];
        const __half2* h0 = (const __half2*)&r0;
#pragma unroll
        for (int q = 0; q < 4; ++q) {
            float2 f0 = __half22float2(h0[q]);
            acc[2 * q + 0] += w0 * f0.x;
            acc[2 * q + 1] += w0 * f0.y;
        }
    }
    __half2 tmp[4];
    tmp[0] = __floats2half2_rn(acc[0], acc[1]);
    tmp[1] = __floats2half2_rn(acc[2], acc[3]);
    tmp[2] = __floats2half2_rn(acc[4], acc[5]);
    tmp[3] = __floats2half2_rn(acc[6], acc[7]);
    ((float4*)(out + (size_t)node * 64))[ln] = *(float4*)tmp;
}

// ---------- prop32: 4-lane groups, 16 nodes/wave (float4 loads), unroll x4 ----------
// Doubles independent walk-chains per wave vs 8-lane (same instr·lane per edge).
template <bool F32OUT>
__global__ __launch_bounds__(256) void prop_gather32(const __half* __restrict__ t,
                                                     const int* __restrict__ rowptr,
                                                     const int2* __restrict__ colw,
                                                     const void* __restrict__ addin,
                                                     void* __restrict__ outv, int nnodes) {
    int grp = threadIdx.x >> 2;          // 0..63 within block
    int ln = threadIdx.x & 3;            // 16B chunk: ch 8*ln .. 8*ln+7
    int node = blockIdx.x * 64 + grp;
    if (node >= nnodes) return;
    int s = rowptr[node];
    int e = rowptr[node + 1];
    float acc[8] = {0.f, 0.f, 0.f, 0.f, 0.f, 0.f, 0.f, 0.f};
    int i = s;
    for (; i + 3 < e; i += 4) {
        int2 cw0 = colw[i];
        int2 cw1 = colw[i + 1];
        int2 cw2 = colw[i + 2];
        int2 cw3 = colw[i + 3];
        float4 r0 = ((const float4*)(t + (size_t)cw0.x * 32))[ln];
        float4 r1 = ((const float4*)(t + (size_t)cw1.x * 32))[ln];
        float4 r2 = ((const float4*)(t + (size_t)cw2.x * 32))[ln];
        float4 r3 = ((const float4*)(t + (size_t)cw3.x * 32))[ln];
        float w0 = __int_as_float(cw0.y);
        float w1 = __int_as_float(cw1.y);
        float w2 = __int_as_float(cw2.y);
        float w3 = __int_as_float(cw3.y);
        const __half2* h0 = (const __half2*)&r0;
        const __half2* h1 = (const __half2*)&r1;
        const __half2* h2 = (const __half2*)&r2;
        const __half2* h3 = (const __half2*)&r3;
#pragma unroll
        for (int q = 0; q < 4; ++q) {
            float2 f0 = __half22float2(h0[q]);
            float2 f1 = __half22float2(h1[q]);
            float2 f2 = __half22float2(h2[q]);
            float2 f3 = __half22float2(h3[q]);
            acc[2 * q + 0] += w0 * f0.x + w1 * f1.x + w2 * f2.x + w3 * f3.x;
            acc[2 * q + 1] += w0 * f0.y + w1 * f1.y + w2 * f2.y + w3 * f3.y;
        }
    }
    for (; i < e; ++i) {
        int2 cw0 = colw[i];
        float w0 = __int_as_float(cw0.y);
        float4 r0 = ((const float4*)(t + (size_t)cw0.x * 32))[ln];
        const __half2* h0 = (const __half2*)&r0;
#pragma unroll
        for (int q = 0; q < 4; ++q) {
            float2 f0 = __half22float2(h0[q]);
            acc[2 * q + 0] += w0 * f0.x;
            acc[2 * q + 1] += w0 * f0.y;
        }
    }
    if (F32OUT) {
        const float* add = (const float*)addin;
        float* out = (float*)outv;
        float4 a0 = ((const float4*)(add + (size_t)node * 32))[ln * 2 + 0];
        float4 a1 = ((const float4*)(add + (size_t)node * 32))[ln * 2 + 1];
        a0.x += acc[0]; a0.y += acc[1]; a0.z += acc[2]; a0.w += acc[3];
        a1.x += acc[4]; a1.y += acc[5]; a1.z += acc[6]; a1.w += acc[7];
        ((float4*)(out + (size_t)node * 32))[ln * 2 + 0] = a0;
        ((float4*)(out + (size_t)node * 32))[ln * 2 + 1] = a1;
    } else {
        const __half* add = (const __half*)addin;
        __half* out = (__half*)outv;
        float4 raw = ((const float4*)(add + (size_t)node * 32))[ln];
        const __half2* hp = (const __half2*)&raw;
        float2 a0 = __half22float2(hp[0]);
        float2 a1 = __half22float2(hp[1]);
        float2 a2 = __half22float2(hp[2]);
        float2 a3 = __half22float2(hp[3]);
        __half2 tmp[4];
        tmp[0] = __floats2half2_rn(acc[0] + a0.x, acc[1] + a0.y);
        tmp[1] = __floats2half2_rn(acc[2] + a1.x, acc[3] + a1.y);
        tmp[2] = __floats2half2_rn(acc[4] + a2.x, acc[5] + a2.y);
        tmp[3] = __floats2half2_rn(acc[6] + a3.x, acc[7] + a3.y);
        ((float4*)(out + (size_t)node * 32))[ln] = *(float4*)tmp;
    }
}

// ---------- FUSED both-layer MFMA GEMM ----------
__global__ __launch_bounds__(256) void gemm_fused(const __half* __restrict__ A0,
                                                  const __half* __restrict__ A1,
                                                  const __half* __restrict__ A2,
                                                  const __half* __restrict__ W1f,
                                                  const float* __restrict__ b1,
                                                  const __half* __restrict__ W2f,
                                                  const float* __restrict__ b2,
                                                  float* __restrict__ P0,
                                                  __half* __restrict__ G1,
                                                  __half* __restrict__ G2, int nnodes) {
    __shared__ __align__(16) __half htile[4][16 * 72];   // 9 KB
    const int wave = threadIdx.x >> 6;
    const int lane = threadIdx.x & 63;
    const int node0 = blockIdx.x * 64 + wave * 16;
    const int m = lane & 15;
    const int quad = lane >> 4;
    int arow = node0 + m;
    if (arow >= nnodes) arow = nnodes - 1;   // clamp: garbage rows never stored globally

    // ---- layer 1 ----
    const __half* Ap[3] = {A0, A1, A2};
    f16x8 a[6];
#pragma unroll
    for (int kh = 0; kh < 6; ++kh) {
        const __half* A = Ap[kh >> 1];
        a[kh] = *(const f16x8*)(A + (size_t)arow * 64 + ((kh & 1) << 5) + (quad << 3));
    }
    __half* ht = htile[wave];
#pragma unroll
    for (int ct = 0; ct < 4; ++ct) {
        f32x4 acc = {0.f, 0.f, 0.f, 0.f};
#pragma unroll
        for (int kh = 0; kh < 6; ++kh) {
            f16x8 b = *(const f16x8*)(W1f + ((size_t)(ct * 6 + kh) * 64 + lane) * 8);
            acc = __builtin_amdgcn_mfma_f32_16x16x32_f16(a[kh], b, acc, 0, 0, 0);
        }
        int col = (ct << 4) | m;
        float bias = b1[col];
#pragma unroll
        for (int r = 0; r < 4; ++r) {
            ht[(quad * 4 + r) * 72 + col] = __float2half(fmaxf(acc[r] + bias, 0.f));
        }
    }
    __syncthreads();

    // ---- layer 2: A-frags straight from the LDS tile ----
    f16x8 h0 = *(const f16x8*)(ht + m * 72 + (quad << 3));
    f16x8 h1 = *(const f16x8*)(ht + m * 72 + 32 + (quad << 3));
#pragma unroll
    for (int ct = 0; ct < 6; ++ct) {
        f32x4 acc = {0.f, 0.f, 0.f, 0.f};
        f16x8 b0 = *(const f16x8*)(W2f + ((size_t)(ct * 2 + 0) * 64 + lane) * 8);
        f16x8 b1v = *(const f16x8*)(W2f + ((size_t)(ct * 2 + 1) * 64 + lane) * 8);
        acc = __builtin_amdgcn_mfma_f32_16x16x32_f16(h0, b0, acc, 0, 0, 0);
        acc = __builtin_amdgcn_mfma_f32_16x16x32_f16(h1, b1v, acc, 0, 0, 0);
        int seg = ct >> 1;                      // wave-uniform
        int c = ((ct & 1) << 4) | m;            // col within segment
#pragma unroll
        for (int r = 0; r < 4; ++r) {
            int n = node0 + (quad << 2) + r;
            if (n >= nnodes) continue;
            float v = acc[r];
            if (seg == 0)      P0[(size_t)n * 32 + c] = v + b2[c];
            else if (seg == 1) G1[(size_t)n * 32 + c] = __float2half(v);
            else               G2[(size_t)n * 32 + c] = __float2half(v);
        }
    }
}

extern "C" void kernel_launch(void* const* d_in, const int* in_sizes, int n_in,
                              void* d_out, int out_size, void* d_ws, size_t ws_size,
                              hipStream_t stream) {
    const float* x  = (const float*)d_in[0];
    const int*   ei = (const int*)d_in[1];
    const float* W1 = (const float*)d_in[2];
    const float* b1 = (const float*)d_in[3];
    const float* W2 = (const float*)d_in[4];
    const float* b2 = (const float*)d_in[5];
    float* out = (float*)d_out;

    const int NN = N_NODES_C;
    const int NE = N_EDGES_C;
    const size_t HFEAT_BYTES = (size_t)NN * 64 * sizeof(__half);
    const size_t H32_BYTES = (size_t)NN * 32 * sizeof(__half);

    char* ws = (char*)d_ws;
    size_t off = 0;
    auto alloc = [&](size_t bytes) -> void* {
        void* p = ws + off;
        off += (bytes + 255) & ~(size_t)255;
        return p;
    };
    int*    bucket_cnt  = (int*)alloc((size_t)NBUK * 4);
    int*    bucket_base = (int*)alloc((size_t)(NBUK + 1) * 4);
    int*    bucket_next = (int*)alloc((size_t)NBUK * 4);
    int*    rowptr      = (int*)alloc((size_t)(NN + 1) * 4);
    float*  dis         = (float*)alloc((size_t)NN * 4);
    int*    staged      = (int*)alloc((size_t)NE * 4);
    int2*   colw        = (int2*)alloc((size_t)NE * 8);
    __half* xh          = (__half*)alloc(HFEAT_BYTES);
    __half* T1h         = (__half*)alloc(HFEAT_BYTES);   // layer1: T1; layer2: G1
    __half* T2h         = (__half*)alloc(HFEAT_BYTES);   // layer1: T2; layer2: G2
    __half* Qh          = (__half*)alloc(H32_BYTES);
    float*  P0          = (float*)alloc((size_t)NN * 32 * 4);
    __half* W1f         = (__half*)alloc((size_t)4 * 6 * 64 * 8 * 2);   // 24 KB
    __half* W2f         = (__half*)alloc((size_t)6 * 2 * 64 * 8 * 2);   // 12 KB

    const int PROPB = (NN + 31) / 32;     // prop64: 32 nodes/block
    const int PROP32B = (NN + 63) / 64;   // prop32: 64 nodes/block
    const int CONV4 = NN * 64 / 4;
    const int CONVB = (CONV4 + 255) / 256;
    const int BINB = (NE + CHUNK - 1) / CHUNK;
    const int GEMMB = (NN + 63) / 64;
    const int FOLDB = 1 + (18432 + 255) / 256;

    // ---- CSR build (bucket-atomic) + weight packing + x->fp16 ----
    hipMemsetAsync(bucket_cnt, 0, (size_t)NBUK * 4, stream);
    hist_f2h<<<BINB + CONVB, 256, 0, stream>>>(ei, bucket_cnt, x, xh, NE, CONV4, BINB);
    scan_fold<<<FOLDB, 256, 0, stream>>>(bucket_cnt, bucket_base, bucket_next, NBUK,
                                         W1, W2, W1f, W2f);
    bin_stage<<<BINB, 256, 0, stream>>>(ei, bucket_next, staged, NE);
    bin_count<<<NBUK, 256, 0, stream>>>(staged, bucket_base, rowptr, dis, NN, NE);
    bin_place<<<NBUK, 256, 0, stream>>>(staged, rowptr, dis, colw, NN);

    // ---- layer 1 props, then fused both-layer GEMM ----
    prop_gather_h<<<PROPB, 256, 0, stream>>>(xh, rowptr, colw, T1h, NN);
    prop_gather_h<<<PROPB, 256, 0, stream>>>(T1h, rowptr, colw, T2h, NN);
    gemm_fused<<<GEMMB, 256, 0, stream>>>(xh, T1h, T2h, W1f, b1, W2f, b2, P0, T1h, T2h, NN);

    // ---- layer 2 (factored): out = P0 + prop(G1 + prop(G2)) ----
    prop_gather32<false><<<PROP32B, 256, 0, stream>>>(T2h, rowptr, colw, T1h, Qh, NN);
    prop_gather32<true><<<PROP32B, 256, 0, stream>>>(Qh, rowptr, colw, P0, out, NN);
}